// Round 10
// baseline (232.733 us; speedup 1.0000x reference)
//
#include <hip/hip_runtime.h>

#define NN 50000
#define NE 800000
#define DD 128
#define GG 2048
#define EPS 1e-5f
#define NBUK 196   // ceil(NN/256) dst-buckets of 256 nodes
#define CHUNK 4096 // edges per bin block
#define CAP 5120   // per-bucket slot capacity (mean 4096, sigma ~64)
#define CVTB 3125  // NN*DD/8/256

typedef __attribute__((ext_vector_type(8))) short short8;
typedef __attribute__((ext_vector_type(4))) float floatx4;

__device__ __forceinline__ ushort f2b(float f) {  // fp32 -> bf16 RNE
  uint u = __float_as_uint(f);
  uint r = ((u >> 16) & 1u) + 0x7fffu;
  return (ushort)((u + r) >> 16);
}
__device__ __forceinline__ float b2f(ushort h) {
  return __uint_as_float(((uint)h) << 16);
}
__device__ __forceinline__ float blo(uint u) { return __uint_as_float(u << 16); }
__device__ __forceinline__ float bhi(uint u) { return __uint_as_float(u & 0xffff0000u); }

// ---------------- prep: zero bucket counters, bf16+swizzle weights, BN folds --
__global__ __launch_bounds__(256) void k_pre(
    const float* __restrict__ W11, const float* __restrict__ W12,
    const float* __restrict__ W21, const float* __restrict__ W22,
    const float* __restrict__ b11, const float* __restrict__ g11,
    const float* __restrict__ be11, const float* __restrict__ m11,
    const float* __restrict__ v11,
    const float* __restrict__ b12, const float* __restrict__ g12,
    const float* __restrict__ be12, const float* __restrict__ m12,
    const float* __restrict__ v12,
    const float* __restrict__ b21, const float* __restrict__ g21,
    const float* __restrict__ be21, const float* __restrict__ m21,
    const float* __restrict__ v21,
    const float* __restrict__ b22, const float* __restrict__ g22,
    const float* __restrict__ be22, const float* __restrict__ m22,
    const float* __restrict__ v22,
    ushort* __restrict__ Wb, float* __restrict__ albb,
    int* __restrict__ buk_cnt) {
  int t = threadIdx.x;
  int b = blockIdx.x;
  if (b == 64) {
    buk_cnt[t] = 0;
    if (t < DD) {
      float a;
      a = g11[t] * rsqrtf(v11[t] + EPS);
      albb[0 * DD + t] = a;
      albb[1 * DD + t] = (b11[t] - m11[t]) * a + be11[t];
      a = g12[t] * rsqrtf(v12[t] + EPS);
      albb[2 * DD + t] = a;
      albb[3 * DD + t] = (b12[t] - m12[t]) * a + be12[t];
      a = g21[t] * rsqrtf(v21[t] + EPS);
      albb[4 * DD + t] = a;
      albb[5 * DD + t] = (b21[t] - m21[t]) * a + be21[t];
      a = g22[t] * rsqrtf(v22[t] + EPS);
      albb[6 * DD + t] = a;
      albb[7 * DD + t] = (b22[t] - m22[t]) * a + be22[t];
    }
    return;
  }
  const float* Ws[4] = {W11, W12, W21, W22};
  int widx = b >> 4;
  int idx = (b & 15) * 256 + t;  // 0..4095
  int c = idx >> 5;
  int k0 = (idx & 31) * 4;
  const float* W = Ws[widx];
  ushort4 p;
  p.x = f2b(W[(k0 + 0) * DD + c]);
  p.y = f2b(W[(k0 + 1) * DD + c]);
  p.z = f2b(W[(k0 + 2) * DD + c]);
  p.w = f2b(W[(k0 + 3) * DD + c]);
  *(ushort4*)&Wb[(size_t)widx * DD * DD + c * DD + (k0 ^ ((c & 7) << 3))] = p;
}

// ---------------- fused fp32->bf16 feature convert + edge binning ------------
__global__ __launch_bounds__(256) void k_binC(const float4* __restrict__ x,
                                              short8* __restrict__ xb,
                                              const int* __restrict__ ei,
                                              int* __restrict__ buk_cnt,
                                              uint* __restrict__ buk_pairs) {
  __shared__ int hist[256];
  __shared__ int gbase[256];
  __shared__ int lcur[256];
  int t = threadIdx.x;
  if (blockIdx.x < CVTB) {
    int i = blockIdx.x * 256 + t;
    float4 a = x[2 * i], c = x[2 * i + 1];
    short8 v;
    v[0] = (short)f2b(a.x); v[1] = (short)f2b(a.y);
    v[2] = (short)f2b(a.z); v[3] = (short)f2b(a.w);
    v[4] = (short)f2b(c.x); v[5] = (short)f2b(c.y);
    v[6] = (short)f2b(c.z); v[7] = (short)f2b(c.w);
    xb[i] = v;
    return;
  }
  int blk = blockIdx.x - CVTB;
  int e0 = blk * CHUNK;
  int nE = min(CHUNK, NE - e0);
  hist[t] = 0;
  lcur[t] = 0;
  gbase[t] = 0;
  __syncthreads();
  uint pk[16];
#pragma unroll
  for (int i = 0; i < 16; ++i) {
    int off = i * 256 + t;
    if (off < nE) {
      int e = e0 + off;
      int s = ei[e], d = ei[NE + e];
      int b = d >> 8;
      pk[i] = ((uint)b << 24) | ((uint)(d & 255) << 16) | (uint)s;
      atomicAdd(&hist[b], 1);
    } else {
      pk[i] = 0xffffffffu;
    }
  }
  __syncthreads();
  if (t < NBUK && hist[t] > 0) gbase[t] = atomicAdd(&buk_cnt[t], hist[t]);
  __syncthreads();
#pragma unroll
  for (int i = 0; i < 16; ++i) {
    if (pk[i] != 0xffffffffu) {
      int b = pk[i] >> 24;
      int lo = atomicAdd(&lcur[b], 1);
      int off = gbase[b] + lo;
      if (off < CAP) buk_pairs[(size_t)b * CAP + off] = pk[i];
    }
  }
}

// ---------------- per-bucket CSR fill (bucket scan inlined) ----------------
__global__ __launch_bounds__(256) void k_bfill(const uint* __restrict__ buk_pairs,
                                               const int* __restrict__ buk_cnt,
                                               int* __restrict__ row_ptr,
                                               int* __restrict__ csr_src) {
  __shared__ int sc[256];
  __shared__ int deg[256];
  __shared__ int pos[256];
  int b = blockIdx.x, t = threadIdx.x;
  int c = (t < NBUK) ? min(buk_cnt[t], CAP) : 0;
  sc[t] = c;
  __syncthreads();
  int s1 = c;
  for (int off = 1; off < 256; off <<= 1) {
    int o = (t >= off) ? sc[t - off] : 0;
    __syncthreads();
    s1 += o;
    sc[t] = s1;
    __syncthreads();
  }
  int beg = (b == 0) ? 0 : sc[b - 1];
  int cnt = sc[b] - beg;
  const uint* src = buk_pairs + (size_t)b * CAP;
  deg[t] = 0;
  __syncthreads();
  for (int i = t; i < cnt; i += 256) {
    atomicAdd(&deg[(src[i] >> 16) & 255], 1);
  }
  __syncthreads();
  int d = deg[t];
  int sum = d;
  pos[t] = sum;
  __syncthreads();
  for (int off = 1; off < 256; off <<= 1) {
    int o = (t >= off) ? pos[t - off] : 0;
    __syncthreads();
    sum += o;
    pos[t] = sum;
    __syncthreads();
  }
  int myStart = beg + sum - d;
  int node = b * 256 + t;
  if (node < NN) row_ptr[node] = myStart;
  if (node == NN - 1) row_ptr[NN] = NE;
  __syncthreads();
  pos[t] = myStart;
  __syncthreads();
  for (int i = t; i < cnt; i += 256) {
    uint p = src[i];
    int lo = atomicAdd(&pos[(p >> 16) & 255], 1);
    csr_src[lo] = (int)(p & 0xffffu);
  }
}

// ---------------- fused GIN layer: agg + MLP(bn,relu x2), bf16 ----------------
// 64 rows/block, 4 waves; each wave aggregates its 16 rows into `mid`
// (fp32 accum -> bf16, XOR-swizzled), then reads its A-frags back wave-locally.
__global__ __launch_bounds__(256) void k_fmlp(const uint* __restrict__ X,
                                              const int* __restrict__ row_ptr,
                                              const int* __restrict__ csr_src,
                                              const ushort* __restrict__ Wb1,
                                              const ushort* __restrict__ Wb2,
                                              const float* __restrict__ albb,
                                              ushort* __restrict__ out) {
  __shared__ ushort Wt[DD * DD];   // 32 KB, reused for W1 then W2
  __shared__ ushort mid[64 * DD];  // 16 KB: agg tile, then GEMM1 output tile
  __shared__ float al1[DD], bb1[DD], al2[DD], bb2[DD];
  int t = threadIdx.x;
  for (int ii = t; ii < 2048; ii += 256) ((short8*)Wt)[ii] = ((const short8*)Wb1)[ii];
  if (t < DD) {
    al1[t] = albb[0 * DD + t];
    bb1[t] = albb[1 * DD + t];
    al2[t] = albb[2 * DD + t];
    bb2[t] = albb[3 * DD + t];
  }
  int w = t >> 6, l = t & 63;
  int lr = l & 15, lg = l >> 4;
  int rowBase = blockIdx.x * 64 + w * 16;
  uint* midu = (uint*)mid;

  // ---- gather prologue: aggregate 16 rows per wave into mid ----
  for (int r = 0; r < 16; ++r) {
    int nd = min(rowBase + r, NN - 1);
    uint s0 = X[(size_t)nd * 64 + l];
    float ax = blo(s0), ay = bhi(s0);
    int beg = row_ptr[nd], end = row_ptr[nd + 1];
    for (int i = beg; i < end; i += 64) {
      int idx = i + l;
      int my = (idx < end) ? __builtin_nontemporal_load(csr_src + idx) : 0;
      int cnt = min(64, end - i);
      int j = 0;
      for (; j + 8 <= cnt; j += 8) {
        int n0 = __shfl(my, j + 0);
        int n1 = __shfl(my, j + 1);
        int n2 = __shfl(my, j + 2);
        int n3 = __shfl(my, j + 3);
        int n4 = __shfl(my, j + 4);
        int n5 = __shfl(my, j + 5);
        int n6 = __shfl(my, j + 6);
        int n7 = __shfl(my, j + 7);
        uint v0 = X[(size_t)n0 * 64 + l];
        uint v1 = X[(size_t)n1 * 64 + l];
        uint v2 = X[(size_t)n2 * 64 + l];
        uint v3 = X[(size_t)n3 * 64 + l];
        uint v4 = X[(size_t)n4 * 64 + l];
        uint v5 = X[(size_t)n5 * 64 + l];
        uint v6 = X[(size_t)n6 * 64 + l];
        uint v7 = X[(size_t)n7 * 64 + l];
        ax += blo(v0); ay += bhi(v0);
        ax += blo(v1); ay += bhi(v1);
        ax += blo(v2); ay += bhi(v2);
        ax += blo(v3); ay += bhi(v3);
        ax += blo(v4); ay += bhi(v4);
        ax += blo(v5); ay += bhi(v5);
        ax += blo(v6); ay += bhi(v6);
        ax += blo(v7); ay += bhi(v7);
      }
      for (; j + 4 <= cnt; j += 4) {
        int n0 = __shfl(my, j + 0);
        int n1 = __shfl(my, j + 1);
        int n2 = __shfl(my, j + 2);
        int n3 = __shfl(my, j + 3);
        uint v0 = X[(size_t)n0 * 64 + l];
        uint v1 = X[(size_t)n1 * 64 + l];
        uint v2 = X[(size_t)n2 * 64 + l];
        uint v3 = X[(size_t)n3 * 64 + l];
        ax += blo(v0); ay += bhi(v0);
        ax += blo(v1); ay += bhi(v1);
        ax += blo(v2); ay += bhi(v2);
        ax += blo(v3); ay += bhi(v3);
      }
      for (; j < cnt; ++j) {
        int s = __shfl(my, j);
        uint v = X[(size_t)s * 64 + l];
        ax += blo(v);
        ay += bhi(v);
      }
    }
    int mrow = w * 16 + r;
    // uint index: col-pair l, swizzled by row (ushort swizzle (mrow&7)<<3 = uint <<2)
    midu[mrow * 64 + (l ^ ((mrow & 7) << 2))] = (uint)f2b(ax) | ((uint)f2b(ay) << 16);
  }
  __syncthreads();  // Wt staged (and mid, though mid is wave-local)

  // ---- load A-frags from mid (wave-local rows) ----
  int mr = w * 16 + lr;
  int msw = (mr & 7) << 3;
  const ushort* mrp = mid + mr * DD;
  short8 a0 = *(const short8*)(mrp + ((0 * 32 + lg * 8) ^ msw));
  short8 a1 = *(const short8*)(mrp + ((1 * 32 + lg * 8) ^ msw));
  short8 a2 = *(const short8*)(mrp + ((2 * 32 + lg * 8) ^ msw));
  short8 a3 = *(const short8*)(mrp + ((3 * 32 + lg * 8) ^ msw));

  // ---- GEMM1 -> mid (overwrites wave-local rows; a-frags already in regs) ----
  int mrowb = w * 16;
#pragma unroll
  for (int ct = 0; ct < 8; ++ct) {
    int c = ct * 16 + lr;
    int sw = (c & 7) << 3;
    const ushort* wr = Wt + c * DD;
    short8 b0 = *(const short8*)(wr + ((0 * 32 + lg * 8) ^ sw));
    short8 b1 = *(const short8*)(wr + ((1 * 32 + lg * 8) ^ sw));
    short8 b2 = *(const short8*)(wr + ((2 * 32 + lg * 8) ^ sw));
    short8 b3 = *(const short8*)(wr + ((3 * 32 + lg * 8) ^ sw));
    floatx4 acc = {0.f, 0.f, 0.f, 0.f};
    acc = __builtin_amdgcn_mfma_f32_16x16x32_bf16(a0, b0, acc, 0, 0, 0);
    acc = __builtin_amdgcn_mfma_f32_16x16x32_bf16(a1, b1, acc, 0, 0, 0);
    acc = __builtin_amdgcn_mfma_f32_16x16x32_bf16(a2, b2, acc, 0, 0, 0);
    acc = __builtin_amdgcn_mfma_f32_16x16x32_bf16(a3, b3, acc, 0, 0, 0);
    float alc = al1[c], bbc = bb1[c];
#pragma unroll
    for (int reg = 0; reg < 4; ++reg) {
      int row = mrowb + lg * 4 + reg;
      mid[row * DD + (c ^ ((row & 7) << 3))] = f2b(fmaxf(acc[reg] * alc + bbc, 0.f));
    }
  }
  __syncthreads();  // all W1 reads done before restage

  // mid C-frags (reg) + restage W2 into Wt
  short8 c0 = *(const short8*)(mrp + ((0 * 32 + lg * 8) ^ msw));
  short8 c1 = *(const short8*)(mrp + ((1 * 32 + lg * 8) ^ msw));
  short8 c2 = *(const short8*)(mrp + ((2 * 32 + lg * 8) ^ msw));
  short8 c3 = *(const short8*)(mrp + ((3 * 32 + lg * 8) ^ msw));
  for (int ii = t; ii < 2048; ii += 256) ((short8*)Wt)[ii] = ((const short8*)Wb2)[ii];
  __syncthreads();

  // ---- GEMM2 -> global ----
#pragma unroll
  for (int ct = 0; ct < 8; ++ct) {
    int c = ct * 16 + lr;
    int sw = (c & 7) << 3;
    const ushort* wr = Wt + c * DD;
    short8 b0 = *(const short8*)(wr + ((0 * 32 + lg * 8) ^ sw));
    short8 b1 = *(const short8*)(wr + ((1 * 32 + lg * 8) ^ sw));
    short8 b2 = *(const short8*)(wr + ((2 * 32 + lg * 8) ^ sw));
    short8 b3 = *(const short8*)(wr + ((3 * 32 + lg * 8) ^ sw));
    floatx4 acc = {0.f, 0.f, 0.f, 0.f};
    acc = __builtin_amdgcn_mfma_f32_16x16x32_bf16(c0, b0, acc, 0, 0, 0);
    acc = __builtin_amdgcn_mfma_f32_16x16x32_bf16(c1, b1, acc, 0, 0, 0);
    acc = __builtin_amdgcn_mfma_f32_16x16x32_bf16(c2, b2, acc, 0, 0, 0);
    acc = __builtin_amdgcn_mfma_f32_16x16x32_bf16(c3, b3, acc, 0, 0, 0);
    float alc = al2[c], bbc = bb2[c];
#pragma unroll
    for (int reg = 0; reg < 4; ++reg) {
      int r = rowBase - w * 16 + w * 16 + lg * 4 + reg;  // == rowBase + lg*4 + reg
      int rr = rowBase + lg * 4 + reg;
      (void)r;
      if (rr < NN) {
        out[(size_t)rr * DD + c] = f2b(fmaxf(acc[reg] * alc + bbc, 0.f));
      }
    }
  }
}

// ---------------- fused mean-pool + classifier (batch sorted) ----------------
__device__ __forceinline__ int lb(const int* __restrict__ a, int n, int v) {
  int lo = 0, hi = n;
  while (lo < hi) {
    int mid = (lo + hi) >> 1;
    if (a[mid] < v) lo = mid + 1;
    else hi = mid;
  }
  return lo;
}

__global__ __launch_bounds__(128) void k_poolcls(const ushort* __restrict__ h,
                                                 const int* __restrict__ batch,
                                                 const float* __restrict__ wc1,
                                                 const float* __restrict__ bc1,
                                                 const float* __restrict__ gc1,
                                                 const float* __restrict__ bec1,
                                                 const float* __restrict__ mc1,
                                                 const float* __restrict__ vc1,
                                                 const float* __restrict__ wc2,
                                                 const float* __restrict__ bc2,
                                                 float* __restrict__ outp) {
  __shared__ int sb[2];
  __shared__ float ps[DD];
  __shared__ float hh[64];
  int g = blockIdx.x, t = threadIdx.x;
  if (t < 2) sb[t] = lb(batch, NN, g + t);
  __syncthreads();
  int beg = sb[0], end = sb[1];
  float acc = 0.f;
  int n = beg;
  for (; n + 4 <= end; n += 4) {
    float x0 = b2f(h[(size_t)(n + 0) * DD + t]);
    float x1 = b2f(h[(size_t)(n + 1) * DD + t]);
    float x2 = b2f(h[(size_t)(n + 2) * DD + t]);
    float x3 = b2f(h[(size_t)(n + 3) * DD + t]);
    acc += x0 + x1 + x2 + x3;
  }
  for (; n < end; ++n) acc += b2f(h[(size_t)n * DD + t]);
  float inv = 1.0f / fmaxf((float)(end - beg), 1.0f);
  ps[t] = acc * inv;
  __syncthreads();
  if (t < 64) {
    float a2 = 0.f;
#pragma unroll 8
    for (int k = 0; k < DD; ++k) a2 += ps[k] * wc1[k * 64 + t];
    float a = gc1[t] * rsqrtf(vc1[t] + EPS);
    float b2 = (bc1[t] - mc1[t]) * a + bec1[t];
    hh[t] = fmaxf(a2 * a + b2, 0.f);
  }
  __syncthreads();
  if (t < 2) {
    float a2 = bc2[t];
#pragma unroll
    for (int k = 0; k < 64; ++k) a2 += hh[k] * wc2[k * 2 + t];
    outp[g * 2 + t] = a2;
  }
}

extern "C" void kernel_launch(void* const* d_in, const int* in_sizes, int n_in,
                              void* d_out, int out_size, void* d_ws, size_t ws_size,
                              hipStream_t stream) {
  const float* x = (const float*)d_in[0];
  const int* ei = (const int*)d_in[1];
  const int* batch = (const int*)d_in[2];
  const float* w11 = (const float*)d_in[3];
  const float* b11 = (const float*)d_in[4];
  const float* g11 = (const float*)d_in[5];
  const float* be11 = (const float*)d_in[6];
  const float* m11 = (const float*)d_in[7];
  const float* v11 = (const float*)d_in[8];
  const float* w12 = (const float*)d_in[9];
  const float* b12 = (const float*)d_in[10];
  const float* g12 = (const float*)d_in[11];
  const float* be12 = (const float*)d_in[12];
  const float* m12 = (const float*)d_in[13];
  const float* v12 = (const float*)d_in[14];
  const float* w21 = (const float*)d_in[15];
  const float* b21 = (const float*)d_in[16];
  const float* g21 = (const float*)d_in[17];
  const float* be21 = (const float*)d_in[18];
  const float* m21 = (const float*)d_in[19];
  const float* v21 = (const float*)d_in[20];
  const float* w22 = (const float*)d_in[21];
  const float* b22 = (const float*)d_in[22];
  const float* g22 = (const float*)d_in[23];
  const float* be22 = (const float*)d_in[24];
  const float* m22 = (const float*)d_in[25];
  const float* v22 = (const float*)d_in[26];
  const float* wc1 = (const float*)d_in[27];
  const float* bc1 = (const float*)d_in[28];
  const float* gc1 = (const float*)d_in[29];
  const float* bec1 = (const float*)d_in[30];
  const float* mc1 = (const float*)d_in[31];
  const float* vc1 = (const float*)d_in[32];
  const float* wc2 = (const float*)d_in[33];
  const float* bc2 = (const float*)d_in[34];

  const size_t NB = (size_t)NN * DD;  // ushort elements per feature buffer
  ushort* XB = (ushort*)d_ws;
  ushort* H1 = XB + NB;
  ushort* H2 = H1 + NB;
  int* row_ptr = (int*)(H2 + NB);      // NN+1
  int* buk_cnt = row_ptr + NN + 1;     // 256 (196 used)
  int* buk_base = buk_cnt + 256;       // spare
  int* csr_src = buk_base + 256;       // NE
  uint* buk_pairs = (uint*)(csr_src + NE);          // NBUK*CAP ~= 1.0M
  ushort* Wb = (ushort*)(buk_pairs + (size_t)NBUK * CAP);  // 4*16384
  float* albb = (float*)(Wb + 4 * DD * DD);         // 8*128

  const int gemmBlocks = (NN + 63) / 64;  // 782

  // ---- prep + convert/bin + fill ----
  k_pre<<<65, 256, 0, stream>>>(w11, w12, w21, w22,
                                b11, g11, be11, m11, v11,
                                b12, g12, be12, m12, v12,
                                b21, g21, be21, m21, v21,
                                b22, g22, be22, m22, v22,
                                Wb, albb, buk_cnt);
  k_binC<<<CVTB + NBUK, 256, 0, stream>>>((const float4*)x, (short8*)XB, ei,
                                          buk_cnt, buk_pairs);
  k_bfill<<<NBUK, 256, 0, stream>>>(buk_pairs, buk_cnt, row_ptr, csr_src);

  // ---- GIN layer 1 (fused agg + MLP) ----
  k_fmlp<<<gemmBlocks, 256, 0, stream>>>((const uint*)XB, row_ptr, csr_src,
                                         Wb, Wb + DD * DD, albb, H1);

  // ---- GIN layer 2 ----
  k_fmlp<<<gemmBlocks, 256, 0, stream>>>((const uint*)H1, row_ptr, csr_src,
                                         Wb + 2 * DD * DD, Wb + 3 * DD * DD,
                                         albb + 4 * DD, H2);

  // ---- fused mean pool + classifier ----
  k_poolcls<<<GG, 128, 0, stream>>>(H2, batch, wc1, bc1, gc1, bec1, mc1, vc1,
                                    wc2, bc2, (float*)d_out);
}

// Round 11
// 157.388 us; speedup vs baseline: 1.4787x; 1.4787x over previous
//
#include <hip/hip_runtime.h>

#define NN 50000
#define NE 800000
#define DD 128
#define GG 2048
#define EPS 1e-5f
#define NBUK 196   // ceil(NN/256) dst-buckets of 256 nodes
#define CHUNK 4096 // edges per bin block
#define CAP 5120   // per-bucket slot capacity (mean 4096, sigma ~64)
#define CVTB 3125  // NN*DD/8/256

typedef __attribute__((ext_vector_type(8))) short short8;
typedef __attribute__((ext_vector_type(4))) float floatx4;

__device__ __forceinline__ ushort f2b(float f) {  // fp32 -> bf16 RNE
  uint u = __float_as_uint(f);
  uint r = ((u >> 16) & 1u) + 0x7fffu;
  return (ushort)((u + r) >> 16);
}
__device__ __forceinline__ float b2f(ushort h) {
  return __uint_as_float(((uint)h) << 16);
}
__device__ __forceinline__ float blo(uint u) { return __uint_as_float(u << 16); }
__device__ __forceinline__ float bhi(uint u) { return __uint_as_float(u & 0xffff0000u); }

// ---------------- prep: zero bucket counters, bf16+swizzle weights, BN folds --
__global__ __launch_bounds__(256) void k_pre(
    const float* __restrict__ W11, const float* __restrict__ W12,
    const float* __restrict__ W21, const float* __restrict__ W22,
    const float* __restrict__ b11, const float* __restrict__ g11,
    const float* __restrict__ be11, const float* __restrict__ m11,
    const float* __restrict__ v11,
    const float* __restrict__ b12, const float* __restrict__ g12,
    const float* __restrict__ be12, const float* __restrict__ m12,
    const float* __restrict__ v12,
    const float* __restrict__ b21, const float* __restrict__ g21,
    const float* __restrict__ be21, const float* __restrict__ m21,
    const float* __restrict__ v21,
    const float* __restrict__ b22, const float* __restrict__ g22,
    const float* __restrict__ be22, const float* __restrict__ m22,
    const float* __restrict__ v22,
    ushort* __restrict__ Wb, float* __restrict__ albb,
    int* __restrict__ buk_cnt) {
  int t = threadIdx.x;
  int b = blockIdx.x;
  if (b == 64) {
    buk_cnt[t] = 0;
    if (t < DD) {
      float a;
      a = g11[t] * rsqrtf(v11[t] + EPS);
      albb[0 * DD + t] = a;
      albb[1 * DD + t] = (b11[t] - m11[t]) * a + be11[t];
      a = g12[t] * rsqrtf(v12[t] + EPS);
      albb[2 * DD + t] = a;
      albb[3 * DD + t] = (b12[t] - m12[t]) * a + be12[t];
      a = g21[t] * rsqrtf(v21[t] + EPS);
      albb[4 * DD + t] = a;
      albb[5 * DD + t] = (b21[t] - m21[t]) * a + be21[t];
      a = g22[t] * rsqrtf(v22[t] + EPS);
      albb[6 * DD + t] = a;
      albb[7 * DD + t] = (b22[t] - m22[t]) * a + be22[t];
    }
    return;
  }
  const float* Ws[4] = {W11, W12, W21, W22};
  int widx = b >> 4;
  int idx = (b & 15) * 256 + t;  // 0..4095
  int c = idx >> 5;
  int k0 = (idx & 31) * 4;
  const float* W = Ws[widx];
  ushort4 p;
  p.x = f2b(W[(k0 + 0) * DD + c]);
  p.y = f2b(W[(k0 + 1) * DD + c]);
  p.z = f2b(W[(k0 + 2) * DD + c]);
  p.w = f2b(W[(k0 + 3) * DD + c]);
  *(ushort4*)&Wb[(size_t)widx * DD * DD + c * DD + (k0 ^ ((c & 7) << 3))] = p;
}

// ---------------- fused fp32->bf16 feature convert + edge binning ------------
__global__ __launch_bounds__(256) void k_binC(const float4* __restrict__ x,
                                              short8* __restrict__ xb,
                                              const int* __restrict__ ei,
                                              int* __restrict__ buk_cnt,
                                              uint* __restrict__ buk_pairs) {
  __shared__ int hist[256];
  __shared__ int gbase[256];
  __shared__ int lcur[256];
  int t = threadIdx.x;
  if (blockIdx.x < CVTB) {
    int i = blockIdx.x * 256 + t;
    float4 a = x[2 * i], c = x[2 * i + 1];
    short8 v;
    v[0] = (short)f2b(a.x); v[1] = (short)f2b(a.y);
    v[2] = (short)f2b(a.z); v[3] = (short)f2b(a.w);
    v[4] = (short)f2b(c.x); v[5] = (short)f2b(c.y);
    v[6] = (short)f2b(c.z); v[7] = (short)f2b(c.w);
    xb[i] = v;
    return;
  }
  int blk = blockIdx.x - CVTB;
  int e0 = blk * CHUNK;
  int nE = min(CHUNK, NE - e0);
  hist[t] = 0;
  lcur[t] = 0;
  gbase[t] = 0;
  __syncthreads();
  uint pk[16];
#pragma unroll
  for (int i = 0; i < 16; ++i) {
    int off = i * 256 + t;
    if (off < nE) {
      int e = e0 + off;
      int s = ei[e], d = ei[NE + e];
      int b = d >> 8;
      pk[i] = ((uint)b << 24) | ((uint)(d & 255) << 16) | (uint)s;
      atomicAdd(&hist[b], 1);
    } else {
      pk[i] = 0xffffffffu;
    }
  }
  __syncthreads();
  if (t < NBUK && hist[t] > 0) gbase[t] = atomicAdd(&buk_cnt[t], hist[t]);
  __syncthreads();
#pragma unroll
  for (int i = 0; i < 16; ++i) {
    if (pk[i] != 0xffffffffu) {
      int b = pk[i] >> 24;
      int lo = atomicAdd(&lcur[b], 1);
      int off = gbase[b] + lo;
      if (off < CAP) buk_pairs[(size_t)b * CAP + off] = pk[i];
    }
  }
}

// ---------------- per-bucket CSR fill (bucket scan inlined) ----------------
__global__ __launch_bounds__(256) void k_bfill(const uint* __restrict__ buk_pairs,
                                               const int* __restrict__ buk_cnt,
                                               int* __restrict__ row_ptr,
                                               int* __restrict__ csr_src) {
  __shared__ int sc[256];
  __shared__ int deg[256];
  __shared__ int pos[256];
  int b = blockIdx.x, t = threadIdx.x;
  int c = (t < NBUK) ? min(buk_cnt[t], CAP) : 0;
  sc[t] = c;
  __syncthreads();
  int s1 = c;
  for (int off = 1; off < 256; off <<= 1) {
    int o = (t >= off) ? sc[t - off] : 0;
    __syncthreads();
    s1 += o;
    sc[t] = s1;
    __syncthreads();
  }
  int beg = (b == 0) ? 0 : sc[b - 1];
  int cnt = sc[b] - beg;
  const uint* src = buk_pairs + (size_t)b * CAP;
  deg[t] = 0;
  __syncthreads();
  for (int i = t; i < cnt; i += 256) {
    atomicAdd(&deg[(src[i] >> 16) & 255], 1);
  }
  __syncthreads();
  int d = deg[t];
  int sum = d;
  pos[t] = sum;
  __syncthreads();
  for (int off = 1; off < 256; off <<= 1) {
    int o = (t >= off) ? pos[t - off] : 0;
    __syncthreads();
    sum += o;
    pos[t] = sum;
    __syncthreads();
  }
  int myStart = beg + sum - d;
  int node = b * 256 + t;
  if (node < NN) row_ptr[node] = myStart;
  if (node == NN - 1) row_ptr[NN] = NE;
  __syncthreads();
  pos[t] = myStart;
  __syncthreads();
  for (int i = t; i < cnt; i += 256) {
    uint p = src[i];
    int lo = atomicAdd(&pos[(p >> 16) & 255], 1);
    csr_src[lo] = (int)(p & 0xffffu);
  }
}

// ---------------- aggregation: out[n] = x[n] + sum_{j->n} x[j] ----------------
// one wave per node; lane owns 2 bf16 cols (uint); 8-deep gather unroll.
// NOTE (R10 lesson): keep this kernel LDS-free / high-occupancy — the gather is
// latency-bound; fusing it into the 50KB-LDS MLP kernel cost 2.3x (occ 60->18%).
__global__ __launch_bounds__(256) void k_agg(const uint* __restrict__ X,
                                             const int* __restrict__ row_ptr,
                                             const int* __restrict__ csr_src,
                                             uint* __restrict__ out) {
  int node = (blockIdx.x * 256 + threadIdx.x) >> 6;
  if (node >= NN) return;
  int lane = threadIdx.x & 63;
  uint s0 = X[(size_t)node * 64 + lane];
  float ax = blo(s0), ay = bhi(s0);
  int beg = row_ptr[node], end = row_ptr[node + 1];
  for (int i = beg; i < end; i += 64) {
    int idx = i + lane;
    int my = (idx < end) ? __builtin_nontemporal_load(csr_src + idx) : 0;
    int cnt = min(64, end - i);
    int j = 0;
    for (; j + 8 <= cnt; j += 8) {
      int n0 = __shfl(my, j + 0);
      int n1 = __shfl(my, j + 1);
      int n2 = __shfl(my, j + 2);
      int n3 = __shfl(my, j + 3);
      int n4 = __shfl(my, j + 4);
      int n5 = __shfl(my, j + 5);
      int n6 = __shfl(my, j + 6);
      int n7 = __shfl(my, j + 7);
      uint v0 = X[(size_t)n0 * 64 + lane];
      uint v1 = X[(size_t)n1 * 64 + lane];
      uint v2 = X[(size_t)n2 * 64 + lane];
      uint v3 = X[(size_t)n3 * 64 + lane];
      uint v4 = X[(size_t)n4 * 64 + lane];
      uint v5 = X[(size_t)n5 * 64 + lane];
      uint v6 = X[(size_t)n6 * 64 + lane];
      uint v7 = X[(size_t)n7 * 64 + lane];
      ax += blo(v0); ay += bhi(v0);
      ax += blo(v1); ay += bhi(v1);
      ax += blo(v2); ay += bhi(v2);
      ax += blo(v3); ay += bhi(v3);
      ax += blo(v4); ay += bhi(v4);
      ax += blo(v5); ay += bhi(v5);
      ax += blo(v6); ay += bhi(v6);
      ax += blo(v7); ay += bhi(v7);
    }
    for (; j + 4 <= cnt; j += 4) {
      int n0 = __shfl(my, j + 0);
      int n1 = __shfl(my, j + 1);
      int n2 = __shfl(my, j + 2);
      int n3 = __shfl(my, j + 3);
      uint v0 = X[(size_t)n0 * 64 + lane];
      uint v1 = X[(size_t)n1 * 64 + lane];
      uint v2 = X[(size_t)n2 * 64 + lane];
      uint v3 = X[(size_t)n3 * 64 + lane];
      ax += blo(v0); ay += bhi(v0);
      ax += blo(v1); ay += bhi(v1);
      ax += blo(v2); ay += bhi(v2);
      ax += blo(v3); ay += bhi(v3);
    }
    for (; j < cnt; ++j) {
      int s = __shfl(my, j);
      uint v = X[(size_t)s * 64 + lane];
      ax += blo(v);
      ay += bhi(v);
    }
  }
  out[(size_t)node * 64 + lane] = (uint)f2b(ax) | ((uint)f2b(ay) << 16);
}

// ---------------- fused MLP: out = relu(bn2(relu(bn1(A@W1))@W2)), bf16 --------
__global__ __launch_bounds__(256) void k_mlp(const ushort* __restrict__ A,
                                             const ushort* __restrict__ Wb1,
                                             const ushort* __restrict__ Wb2,
                                             const float* __restrict__ albb,
                                             ushort* __restrict__ out) {
  __shared__ ushort Wt[DD * DD];   // 32 KB, reused for W1 then W2
  __shared__ ushort mid[64 * DD];  // 16 KB
  __shared__ float al1[DD], bb1[DD], al2[DD], bb2[DD];
  int t = threadIdx.x;
  for (int ii = t; ii < 2048; ii += 256) ((short8*)Wt)[ii] = ((const short8*)Wb1)[ii];
  if (t < DD) {
    al1[t] = albb[0 * DD + t];
    bb1[t] = albb[1 * DD + t];
    al2[t] = albb[2 * DD + t];
    bb2[t] = albb[3 * DD + t];
  }
  int w = t >> 6, l = t & 63;
  int lr = l & 15, lg = l >> 4;
  int rowBase = blockIdx.x * 64 + w * 16;
  int arow = min(rowBase + lr, NN - 1);
  const short8* Ar = (const short8*)(A + (size_t)arow * DD);
  short8 a0 = Ar[0 * 4 + lg];
  short8 a1 = Ar[1 * 4 + lg];
  short8 a2 = Ar[2 * 4 + lg];
  short8 a3 = Ar[3 * 4 + lg];
  __syncthreads();

  // ---- GEMM1 -> mid (LDS) ----
  int mrowb = w * 16;
#pragma unroll
  for (int ct = 0; ct < 8; ++ct) {
    int c = ct * 16 + lr;
    int sw = (c & 7) << 3;
    const ushort* wr = Wt + c * DD;
    short8 b0 = *(const short8*)(wr + ((0 * 32 + lg * 8) ^ sw));
    short8 b1 = *(const short8*)(wr + ((1 * 32 + lg * 8) ^ sw));
    short8 b2 = *(const short8*)(wr + ((2 * 32 + lg * 8) ^ sw));
    short8 b3 = *(const short8*)(wr + ((3 * 32 + lg * 8) ^ sw));
    floatx4 acc = {0.f, 0.f, 0.f, 0.f};
    acc = __builtin_amdgcn_mfma_f32_16x16x32_bf16(a0, b0, acc, 0, 0, 0);
    acc = __builtin_amdgcn_mfma_f32_16x16x32_bf16(a1, b1, acc, 0, 0, 0);
    acc = __builtin_amdgcn_mfma_f32_16x16x32_bf16(a2, b2, acc, 0, 0, 0);
    acc = __builtin_amdgcn_mfma_f32_16x16x32_bf16(a3, b3, acc, 0, 0, 0);
    float alc = al1[c], bbc = bb1[c];
#pragma unroll
    for (int reg = 0; reg < 4; ++reg) {
      int row = mrowb + lg * 4 + reg;
      mid[row * DD + (c ^ ((row & 7) << 3))] = f2b(fmaxf(acc[reg] * alc + bbc, 0.f));
    }
  }
  __syncthreads();  // mid complete; all W1 reads done

  // mid A-frags (reg) + restage W2 into Wt
  int mr = mrowb + lr;
  int msw = (mr & 7) << 3;
  const ushort* mrp = mid + mr * DD;
  short8 c0 = *(const short8*)(mrp + ((0 * 32 + lg * 8) ^ msw));
  short8 c1 = *(const short8*)(mrp + ((1 * 32 + lg * 8) ^ msw));
  short8 c2 = *(const short8*)(mrp + ((2 * 32 + lg * 8) ^ msw));
  short8 c3 = *(const short8*)(mrp + ((3 * 32 + lg * 8) ^ msw));
  for (int ii = t; ii < 2048; ii += 256) ((short8*)Wt)[ii] = ((const short8*)Wb2)[ii];
  __syncthreads();

  // ---- GEMM2 -> global ----
#pragma unroll
  for (int ct = 0; ct < 8; ++ct) {
    int c = ct * 16 + lr;
    int sw = (c & 7) << 3;
    const ushort* wr = Wt + c * DD;
    short8 b0 = *(const short8*)(wr + ((0 * 32 + lg * 8) ^ sw));
    short8 b1 = *(const short8*)(wr + ((1 * 32 + lg * 8) ^ sw));
    short8 b2 = *(const short8*)(wr + ((2 * 32 + lg * 8) ^ sw));
    short8 b3 = *(const short8*)(wr + ((3 * 32 + lg * 8) ^ sw));
    floatx4 acc = {0.f, 0.f, 0.f, 0.f};
    acc = __builtin_amdgcn_mfma_f32_16x16x32_bf16(c0, b0, acc, 0, 0, 0);
    acc = __builtin_amdgcn_mfma_f32_16x16x32_bf16(c1, b1, acc, 0, 0, 0);
    acc = __builtin_amdgcn_mfma_f32_16x16x32_bf16(c2, b2, acc, 0, 0, 0);
    acc = __builtin_amdgcn_mfma_f32_16x16x32_bf16(c3, b3, acc, 0, 0, 0);
    float alc = al2[c], bbc = bb2[c];
#pragma unroll
    for (int reg = 0; reg < 4; ++reg) {
      int r = rowBase + lg * 4 + reg;
      if (r < NN) {
        out[(size_t)r * DD + c] = f2b(fmaxf(acc[reg] * alc + bbc, 0.f));
      }
    }
  }
}

// ---------------- fused mean-pool + classifier (batch sorted) ----------------
// 256 threads: two half-row-range partial sums per column halve the serial chain
__device__ __forceinline__ int lb(const int* __restrict__ a, int n, int v) {
  int lo = 0, hi = n;
  while (lo < hi) {
    int mid = (lo + hi) >> 1;
    if (a[mid] < v) lo = mid + 1;
    else hi = mid;
  }
  return lo;
}

__global__ __launch_bounds__(256) void k_poolcls(const ushort* __restrict__ h,
                                                 const int* __restrict__ batch,
                                                 const float* __restrict__ wc1,
                                                 const float* __restrict__ bc1,
                                                 const float* __restrict__ gc1,
                                                 const float* __restrict__ bec1,
                                                 const float* __restrict__ mc1,
                                                 const float* __restrict__ vc1,
                                                 const float* __restrict__ wc2,
                                                 const float* __restrict__ bc2,
                                                 float* __restrict__ outp) {
  __shared__ int sb[2];
  __shared__ float ps[DD];
  __shared__ float ps2[DD];
  __shared__ float hh[64];
  int g = blockIdx.x, t = threadIdx.x;
  if (t < 2) sb[t] = lb(batch, NN, g + t);
  __syncthreads();
  int beg = sb[0], end = sb[1];
  int c = t & 127;
  int half = t >> 7;  // 0 or 1
  int m = (beg + end) >> 1;
  int lo0 = half ? m : beg;
  int hi0 = half ? end : m;
  float acc = 0.f;
  int n = lo0;
  for (; n + 4 <= hi0; n += 4) {
    float x0 = b2f(h[(size_t)(n + 0) * DD + c]);
    float x1 = b2f(h[(size_t)(n + 1) * DD + c]);
    float x2 = b2f(h[(size_t)(n + 2) * DD + c]);
    float x3 = b2f(h[(size_t)(n + 3) * DD + c]);
    acc += x0 + x1 + x2 + x3;
  }
  for (; n < hi0; ++n) acc += b2f(h[(size_t)n * DD + c]);
  if (half) ps2[c] = acc;
  else ps[c] = acc;
  __syncthreads();
  if (t < DD) {
    float inv = 1.0f / fmaxf((float)(end - beg), 1.0f);
    ps[t] = (ps[t] + ps2[t]) * inv;
  }
  __syncthreads();
  if (t < 64) {
    float a2 = 0.f;
#pragma unroll 8
    for (int k = 0; k < DD; ++k) a2 += ps[k] * wc1[k * 64 + t];
    float a = gc1[t] * rsqrtf(vc1[t] + EPS);
    float b2 = (bc1[t] - mc1[t]) * a + bec1[t];
    hh[t] = fmaxf(a2 * a + b2, 0.f);
  }
  __syncthreads();
  if (t < 2) {
    float a2 = bc2[t];
#pragma unroll
    for (int k = 0; k < 64; ++k) a2 += hh[k] * wc2[k * 2 + t];
    outp[g * 2 + t] = a2;
  }
}

extern "C" void kernel_launch(void* const* d_in, const int* in_sizes, int n_in,
                              void* d_out, int out_size, void* d_ws, size_t ws_size,
                              hipStream_t stream) {
  const float* x = (const float*)d_in[0];
  const int* ei = (const int*)d_in[1];
  const int* batch = (const int*)d_in[2];
  const float* w11 = (const float*)d_in[3];
  const float* b11 = (const float*)d_in[4];
  const float* g11 = (const float*)d_in[5];
  const float* be11 = (const float*)d_in[6];
  const float* m11 = (const float*)d_in[7];
  const float* v11 = (const float*)d_in[8];
  const float* w12 = (const float*)d_in[9];
  const float* b12 = (const float*)d_in[10];
  const float* g12 = (const float*)d_in[11];
  const float* be12 = (const float*)d_in[12];
  const float* m12 = (const float*)d_in[13];
  const float* v12 = (const float*)d_in[14];
  const float* w21 = (const float*)d_in[15];
  const float* b21 = (const float*)d_in[16];
  const float* g21 = (const float*)d_in[17];
  const float* be21 = (const float*)d_in[18];
  const float* m21 = (const float*)d_in[19];
  const float* v21 = (const float*)d_in[20];
  const float* w22 = (const float*)d_in[21];
  const float* b22 = (const float*)d_in[22];
  const float* g22 = (const float*)d_in[23];
  const float* be22 = (const float*)d_in[24];
  const float* m22 = (const float*)d_in[25];
  const float* v22 = (const float*)d_in[26];
  const float* wc1 = (const float*)d_in[27];
  const float* bc1 = (const float*)d_in[28];
  const float* gc1 = (const float*)d_in[29];
  const float* bec1 = (const float*)d_in[30];
  const float* mc1 = (const float*)d_in[31];
  const float* vc1 = (const float*)d_in[32];
  const float* wc2 = (const float*)d_in[33];
  const float* bc2 = (const float*)d_in[34];

  const size_t NB = (size_t)NN * DD;  // ushort elements per feature buffer
  ushort* XB = (ushort*)d_ws;
  ushort* AG = XB + NB;
  ushort* H1 = AG + NB;
  ushort* H2 = H1 + NB;
  int* row_ptr = (int*)(H2 + NB);      // NN+1
  int* buk_cnt = row_ptr + NN + 1;     // 256 (196 used)
  int* buk_base = buk_cnt + 256;       // spare
  int* csr_src = buk_base + 256;       // NE
  uint* buk_pairs = (uint*)(csr_src + NE);          // NBUK*CAP ~= 1.0M
  ushort* Wb = (ushort*)(buk_pairs + (size_t)NBUK * CAP);  // 4*16384
  float* albb = (float*)(Wb + 4 * DD * DD);         // 8*128

  const int gemmBlocks = (NN + 63) / 64;  // 782
  const int aggBlocks = NN * 64 / 256;    // 12500

  // ---- prep + convert/bin + fill ----
  k_pre<<<65, 256, 0, stream>>>(w11, w12, w21, w22,
                                b11, g11, be11, m11, v11,
                                b12, g12, be12, m12, v12,
                                b21, g21, be21, m21, v21,
                                b22, g22, be22, m22, v22,
                                Wb, albb, buk_cnt);
  k_binC<<<CVTB + NBUK, 256, 0, stream>>>((const float4*)x, (short8*)XB, ei,
                                          buk_cnt, buk_pairs);
  k_bfill<<<NBUK, 256, 0, stream>>>(buk_pairs, buk_cnt, row_ptr, csr_src);

  // ---- GIN layer 1 ----
  k_agg<<<aggBlocks, 256, 0, stream>>>((const uint*)XB, row_ptr, csr_src, (uint*)AG);
  k_mlp<<<gemmBlocks, 256, 0, stream>>>(AG, Wb, Wb + DD * DD, albb, H1);

  // ---- GIN layer 2 ----
  k_agg<<<aggBlocks, 256, 0, stream>>>((const uint*)H1, row_ptr, csr_src, (uint*)AG);
  k_mlp<<<gemmBlocks, 256, 0, stream>>>(AG, Wb + 2 * DD * DD, Wb + 3 * DD * DD,
                                        albb + 4 * DD, H2);

  // ---- fused mean pool + classifier ----
  k_poolcls<<<GG, 256, 0, stream>>>(H2, batch, wc1, bc1, gc1, bec1, mc1, vc1,
                                    wc2, bc2, (float*)d_out);
}

// Round 12
// 150.445 us; speedup vs baseline: 1.5470x; 1.0461x over previous
//
#include <hip/hip_runtime.h>

#define NN 50000
#define NE 800000
#define DD 128
#define GG 2048
#define EPS 1e-5f
#define NBUK 196   // ceil(NN/256) dst-buckets of 256 nodes
#define CHUNK 4096 // edges per bin block
#define CAP 5120   // per-bucket slot capacity (mean 4096, sigma ~64)
#define CVTB 3125  // NN*DD/8/256

typedef __attribute__((ext_vector_type(8))) short short8;
typedef __attribute__((ext_vector_type(4))) float floatx4;

__device__ __forceinline__ ushort f2b(float f) {  // fp32 -> bf16 RNE
  uint u = __float_as_uint(f);
  uint r = ((u >> 16) & 1u) + 0x7fffu;
  return (ushort)((u + r) >> 16);
}
__device__ __forceinline__ float b2f(ushort h) {
  return __uint_as_float(((uint)h) << 16);
}
__device__ __forceinline__ float blo(uint u) { return __uint_as_float(u << 16); }
__device__ __forceinline__ float bhi(uint u) { return __uint_as_float(u & 0xffff0000u); }

// ---------------- prep: zero bucket counters, bf16+swizzle weights, BN folds --
__global__ __launch_bounds__(256) void k_pre(
    const float* __restrict__ W11, const float* __restrict__ W12,
    const float* __restrict__ W21, const float* __restrict__ W22,
    const float* __restrict__ b11, const float* __restrict__ g11,
    const float* __restrict__ be11, const float* __restrict__ m11,
    const float* __restrict__ v11,
    const float* __restrict__ b12, const float* __restrict__ g12,
    const float* __restrict__ be12, const float* __restrict__ m12,
    const float* __restrict__ v12,
    const float* __restrict__ b21, const float* __restrict__ g21,
    const float* __restrict__ be21, const float* __restrict__ m21,
    const float* __restrict__ v21,
    const float* __restrict__ b22, const float* __restrict__ g22,
    const float* __restrict__ be22, const float* __restrict__ m22,
    const float* __restrict__ v22,
    ushort* __restrict__ Wb, float* __restrict__ albb,
    int* __restrict__ buk_cnt) {
  int t = threadIdx.x;
  int b = blockIdx.x;
  if (b == 64) {
    buk_cnt[t] = 0;
    if (t < DD) {
      float a;
      a = g11[t] * rsqrtf(v11[t] + EPS);
      albb[0 * DD + t] = a;
      albb[1 * DD + t] = (b11[t] - m11[t]) * a + be11[t];
      a = g12[t] * rsqrtf(v12[t] + EPS);
      albb[2 * DD + t] = a;
      albb[3 * DD + t] = (b12[t] - m12[t]) * a + be12[t];
      a = g21[t] * rsqrtf(v21[t] + EPS);
      albb[4 * DD + t] = a;
      albb[5 * DD + t] = (b21[t] - m21[t]) * a + be21[t];
      a = g22[t] * rsqrtf(v22[t] + EPS);
      albb[6 * DD + t] = a;
      albb[7 * DD + t] = (b22[t] - m22[t]) * a + be22[t];
    }
    return;
  }
  const float* Ws[4] = {W11, W12, W21, W22};
  int widx = b >> 4;
  int idx = (b & 15) * 256 + t;  // 0..4095
  int c = idx >> 5;
  int k0 = (idx & 31) * 4;
  const float* W = Ws[widx];
  ushort4 p;
  p.x = f2b(W[(k0 + 0) * DD + c]);
  p.y = f2b(W[(k0 + 1) * DD + c]);
  p.z = f2b(W[(k0 + 2) * DD + c]);
  p.w = f2b(W[(k0 + 3) * DD + c]);
  *(ushort4*)&Wb[(size_t)widx * DD * DD + c * DD + (k0 ^ ((c & 7) << 3))] = p;
}

// ---------------- fused fp32->bf16 feature convert + edge binning ------------
__global__ __launch_bounds__(256) void k_binC(const float4* __restrict__ x,
                                              short8* __restrict__ xb,
                                              const int* __restrict__ ei,
                                              int* __restrict__ buk_cnt,
                                              uint* __restrict__ buk_pairs) {
  __shared__ int hist[256];
  __shared__ int gbase[256];
  __shared__ int lcur[256];
  int t = threadIdx.x;
  if (blockIdx.x < CVTB) {
    int i = blockIdx.x * 256 + t;
    float4 a = x[2 * i], c = x[2 * i + 1];
    short8 v;
    v[0] = (short)f2b(a.x); v[1] = (short)f2b(a.y);
    v[2] = (short)f2b(a.z); v[3] = (short)f2b(a.w);
    v[4] = (short)f2b(c.x); v[5] = (short)f2b(c.y);
    v[6] = (short)f2b(c.z); v[7] = (short)f2b(c.w);
    xb[i] = v;
    return;
  }
  int blk = blockIdx.x - CVTB;
  int e0 = blk * CHUNK;
  int nE = min(CHUNK, NE - e0);
  hist[t] = 0;
  lcur[t] = 0;
  gbase[t] = 0;
  __syncthreads();
  uint pk[16];
#pragma unroll
  for (int i = 0; i < 16; ++i) {
    int off = i * 256 + t;
    if (off < nE) {
      int e = e0 + off;
      int s = ei[e], d = ei[NE + e];
      int b = d >> 8;
      pk[i] = ((uint)b << 24) | ((uint)(d & 255) << 16) | (uint)s;
      atomicAdd(&hist[b], 1);
    } else {
      pk[i] = 0xffffffffu;
    }
  }
  __syncthreads();
  if (t < NBUK && hist[t] > 0) gbase[t] = atomicAdd(&buk_cnt[t], hist[t]);
  __syncthreads();
#pragma unroll
  for (int i = 0; i < 16; ++i) {
    if (pk[i] != 0xffffffffu) {
      int b = pk[i] >> 24;
      int lo = atomicAdd(&lcur[b], 1);
      int off = gbase[b] + lo;
      if (off < CAP) buk_pairs[(size_t)b * CAP + off] = pk[i];
    }
  }
}

// ---------------- per-bucket CSR fill (bucket scan inlined) ----------------
__global__ __launch_bounds__(256) void k_bfill(const uint* __restrict__ buk_pairs,
                                               const int* __restrict__ buk_cnt,
                                               int* __restrict__ row_ptr,
                                               int* __restrict__ csr_src) {
  __shared__ int sc[256];
  __shared__ int deg[256];
  __shared__ int pos[256];
  int b = blockIdx.x, t = threadIdx.x;
  int c = (t < NBUK) ? min(buk_cnt[t], CAP) : 0;
  sc[t] = c;
  __syncthreads();
  int s1 = c;
  for (int off = 1; off < 256; off <<= 1) {
    int o = (t >= off) ? sc[t - off] : 0;
    __syncthreads();
    s1 += o;
    sc[t] = s1;
    __syncthreads();
  }
  int beg = (b == 0) ? 0 : sc[b - 1];
  int cnt = sc[b] - beg;
  const uint* src = buk_pairs + (size_t)b * CAP;
  deg[t] = 0;
  __syncthreads();
  for (int i = t; i < cnt; i += 256) {
    atomicAdd(&deg[(src[i] >> 16) & 255], 1);
  }
  __syncthreads();
  int d = deg[t];
  int sum = d;
  pos[t] = sum;
  __syncthreads();
  for (int off = 1; off < 256; off <<= 1) {
    int o = (t >= off) ? pos[t - off] : 0;
    __syncthreads();
    sum += o;
    pos[t] = sum;
    __syncthreads();
  }
  int myStart = beg + sum - d;
  int node = b * 256 + t;
  if (node < NN) row_ptr[node] = myStart;
  if (node == NN - 1) row_ptr[NN] = NE;
  __syncthreads();
  pos[t] = myStart;
  __syncthreads();
  for (int i = t; i < cnt; i += 256) {
    uint p = src[i];
    int lo = atomicAdd(&pos[(p >> 16) & 255], 1);
    csr_src[lo] = (int)(p & 0xffffu);
  }
}

// ---------------- aggregation: out[n] = x[n] + sum_{j->n} x[j] ----------------
// TWO nodes per wave (32 lanes each, lane owns 4 bf16 cols via uint2): one vmem
// instruction covers 512 B across two rows -> half the instructions, 2x the
// in-flight bytes vs one-node-per-wave. Keep LDS-free (R10 occupancy lesson).
__global__ __launch_bounds__(256) void k_agg(const uint* __restrict__ X,
                                             const int* __restrict__ row_ptr,
                                             const int* __restrict__ csr_src,
                                             uint* __restrict__ out) {
  int wid = (blockIdx.x * 256 + threadIdx.x) >> 6;
  int l = threadIdx.x & 63;
  int g = l >> 5, sl = l & 31;
  int node = wid * 2 + g;  // NN=50000 even; grid covers exactly
  if (node >= NN) return;
  int base = g * 32;
  const uint2* Xr = (const uint2*)(X + (size_t)node * 64);
  uint2 s0 = Xr[sl];
  float a0 = blo(s0.x), a1 = bhi(s0.x), a2 = blo(s0.y), a3 = bhi(s0.y);
  int beg = row_ptr[node], end = row_ptr[node + 1];
  for (int i = beg; i < end; i += 32) {
    int idx = i + sl;
    int my = (idx < end) ? __builtin_nontemporal_load(csr_src + idx) : 0;
    int cnt = min(32, end - i);
    int j = 0;
    for (; j + 8 <= cnt; j += 8) {
      int n0 = __shfl(my, base + j + 0);
      int n1 = __shfl(my, base + j + 1);
      int n2 = __shfl(my, base + j + 2);
      int n3 = __shfl(my, base + j + 3);
      int n4 = __shfl(my, base + j + 4);
      int n5 = __shfl(my, base + j + 5);
      int n6 = __shfl(my, base + j + 6);
      int n7 = __shfl(my, base + j + 7);
      uint2 v0 = *(const uint2*)(X + (size_t)n0 * 64 + sl * 2);
      uint2 v1 = *(const uint2*)(X + (size_t)n1 * 64 + sl * 2);
      uint2 v2 = *(const uint2*)(X + (size_t)n2 * 64 + sl * 2);
      uint2 v3 = *(const uint2*)(X + (size_t)n3 * 64 + sl * 2);
      uint2 v4 = *(const uint2*)(X + (size_t)n4 * 64 + sl * 2);
      uint2 v5 = *(const uint2*)(X + (size_t)n5 * 64 + sl * 2);
      uint2 v6 = *(const uint2*)(X + (size_t)n6 * 64 + sl * 2);
      uint2 v7 = *(const uint2*)(X + (size_t)n7 * 64 + sl * 2);
      a0 += blo(v0.x); a1 += bhi(v0.x); a2 += blo(v0.y); a3 += bhi(v0.y);
      a0 += blo(v1.x); a1 += bhi(v1.x); a2 += blo(v1.y); a3 += bhi(v1.y);
      a0 += blo(v2.x); a1 += bhi(v2.x); a2 += blo(v2.y); a3 += bhi(v2.y);
      a0 += blo(v3.x); a1 += bhi(v3.x); a2 += blo(v3.y); a3 += bhi(v3.y);
      a0 += blo(v4.x); a1 += bhi(v4.x); a2 += blo(v4.y); a3 += bhi(v4.y);
      a0 += blo(v5.x); a1 += bhi(v5.x); a2 += blo(v5.y); a3 += bhi(v5.y);
      a0 += blo(v6.x); a1 += bhi(v6.x); a2 += blo(v6.y); a3 += bhi(v6.y);
      a0 += blo(v7.x); a1 += bhi(v7.x); a2 += blo(v7.y); a3 += bhi(v7.y);
    }
    for (; j + 4 <= cnt; j += 4) {
      int n0 = __shfl(my, base + j + 0);
      int n1 = __shfl(my, base + j + 1);
      int n2 = __shfl(my, base + j + 2);
      int n3 = __shfl(my, base + j + 3);
      uint2 v0 = *(const uint2*)(X + (size_t)n0 * 64 + sl * 2);
      uint2 v1 = *(const uint2*)(X + (size_t)n1 * 64 + sl * 2);
      uint2 v2 = *(const uint2*)(X + (size_t)n2 * 64 + sl * 2);
      uint2 v3 = *(const uint2*)(X + (size_t)n3 * 64 + sl * 2);
      a0 += blo(v0.x); a1 += bhi(v0.x); a2 += blo(v0.y); a3 += bhi(v0.y);
      a0 += blo(v1.x); a1 += bhi(v1.x); a2 += blo(v1.y); a3 += bhi(v1.y);
      a0 += blo(v2.x); a1 += bhi(v2.x); a2 += blo(v2.y); a3 += bhi(v2.y);
      a0 += blo(v3.x); a1 += bhi(v3.x); a2 += blo(v3.y); a3 += bhi(v3.y);
    }
    for (; j < cnt; ++j) {
      int s = __shfl(my, base + j);
      uint2 v = *(const uint2*)(X + (size_t)s * 64 + sl * 2);
      a0 += blo(v.x); a1 += bhi(v.x); a2 += blo(v.y); a3 += bhi(v.y);
    }
  }
  uint2 o;
  o.x = (uint)f2b(a0) | ((uint)f2b(a1) << 16);
  o.y = (uint)f2b(a2) | ((uint)f2b(a3) << 16);
  *(uint2*)(out + (size_t)node * 64 + sl * 2) = o;
}

// ---------------- fused MLP: out = relu(bn2(relu(bn1(A@W1))@W2)), bf16 --------
__global__ __launch_bounds__(256) void k_mlp(const ushort* __restrict__ A,
                                             const ushort* __restrict__ Wb1,
                                             const ushort* __restrict__ Wb2,
                                             const float* __restrict__ albb,
                                             ushort* __restrict__ out) {
  __shared__ ushort Wt[DD * DD];   // 32 KB, reused for W1 then W2
  __shared__ ushort mid[64 * DD];  // 16 KB
  __shared__ float al1[DD], bb1[DD], al2[DD], bb2[DD];
  int t = threadIdx.x;
  for (int ii = t; ii < 2048; ii += 256) ((short8*)Wt)[ii] = ((const short8*)Wb1)[ii];
  if (t < DD) {
    al1[t] = albb[0 * DD + t];
    bb1[t] = albb[1 * DD + t];
    al2[t] = albb[2 * DD + t];
    bb2[t] = albb[3 * DD + t];
  }
  int w = t >> 6, l = t & 63;
  int lr = l & 15, lg = l >> 4;
  int rowBase = blockIdx.x * 64 + w * 16;
  int arow = min(rowBase + lr, NN - 1);
  const short8* Ar = (const short8*)(A + (size_t)arow * DD);
  short8 a0 = Ar[0 * 4 + lg];
  short8 a1 = Ar[1 * 4 + lg];
  short8 a2 = Ar[2 * 4 + lg];
  short8 a3 = Ar[3 * 4 + lg];
  __syncthreads();

  // ---- GEMM1 -> mid (LDS) ----
  int mrowb = w * 16;
#pragma unroll
  for (int ct = 0; ct < 8; ++ct) {
    int c = ct * 16 + lr;
    int sw = (c & 7) << 3;
    const ushort* wr = Wt + c * DD;
    short8 b0 = *(const short8*)(wr + ((0 * 32 + lg * 8) ^ sw));
    short8 b1 = *(const short8*)(wr + ((1 * 32 + lg * 8) ^ sw));
    short8 b2 = *(const short8*)(wr + ((2 * 32 + lg * 8) ^ sw));
    short8 b3 = *(const short8*)(wr + ((3 * 32 + lg * 8) ^ sw));
    floatx4 acc = {0.f, 0.f, 0.f, 0.f};
    acc = __builtin_amdgcn_mfma_f32_16x16x32_bf16(a0, b0, acc, 0, 0, 0);
    acc = __builtin_amdgcn_mfma_f32_16x16x32_bf16(a1, b1, acc, 0, 0, 0);
    acc = __builtin_amdgcn_mfma_f32_16x16x32_bf16(a2, b2, acc, 0, 0, 0);
    acc = __builtin_amdgcn_mfma_f32_16x16x32_bf16(a3, b3, acc, 0, 0, 0);
    float alc = al1[c], bbc = bb1[c];
#pragma unroll
    for (int reg = 0; reg < 4; ++reg) {
      int row = mrowb + lg * 4 + reg;
      mid[row * DD + (c ^ ((row & 7) << 3))] = f2b(fmaxf(acc[reg] * alc + bbc, 0.f));
    }
  }
  __syncthreads();  // mid complete; all W1 reads done

  // mid A-frags (reg) + restage W2 into Wt
  int mr = mrowb + lr;
  int msw = (mr & 7) << 3;
  const ushort* mrp = mid + mr * DD;
  short8 c0 = *(const short8*)(mrp + ((0 * 32 + lg * 8) ^ msw));
  short8 c1 = *(const short8*)(mrp + ((1 * 32 + lg * 8) ^ msw));
  short8 c2 = *(const short8*)(mrp + ((2 * 32 + lg * 8) ^ msw));
  short8 c3 = *(const short8*)(mrp + ((3 * 32 + lg * 8) ^ msw));
  for (int ii = t; ii < 2048; ii += 256) ((short8*)Wt)[ii] = ((const short8*)Wb2)[ii];
  __syncthreads();

  // ---- GEMM2 -> global ----
#pragma unroll
  for (int ct = 0; ct < 8; ++ct) {
    int c = ct * 16 + lr;
    int sw = (c & 7) << 3;
    const ushort* wr = Wt + c * DD;
    short8 b0 = *(const short8*)(wr + ((0 * 32 + lg * 8) ^ sw));
    short8 b1 = *(const short8*)(wr + ((1 * 32 + lg * 8) ^ sw));
    short8 b2 = *(const short8*)(wr + ((2 * 32 + lg * 8) ^ sw));
    short8 b3 = *(const short8*)(wr + ((3 * 32 + lg * 8) ^ sw));
    floatx4 acc = {0.f, 0.f, 0.f, 0.f};
    acc = __builtin_amdgcn_mfma_f32_16x16x32_bf16(c0, b0, acc, 0, 0, 0);
    acc = __builtin_amdgcn_mfma_f32_16x16x32_bf16(c1, b1, acc, 0, 0, 0);
    acc = __builtin_amdgcn_mfma_f32_16x16x32_bf16(c2, b2, acc, 0, 0, 0);
    acc = __builtin_amdgcn_mfma_f32_16x16x32_bf16(c3, b3, acc, 0, 0, 0);
    float alc = al2[c], bbc = bb2[c];
#pragma unroll
    for (int reg = 0; reg < 4; ++reg) {
      int r = rowBase + lg * 4 + reg;
      if (r < NN) {
        out[(size_t)r * DD + c] = f2b(fmaxf(acc[reg] * alc + bbc, 0.f));
      }
    }
  }
}

// ---------------- fused mean-pool + classifier (batch sorted) ----------------
__device__ __forceinline__ int lb(const int* __restrict__ a, int n, int v) {
  int lo = 0, hi = n;
  while (lo < hi) {
    int mid = (lo + hi) >> 1;
    if (a[mid] < v) lo = mid + 1;
    else hi = mid;
  }
  return lo;
}

__global__ __launch_bounds__(256) void k_poolcls(const ushort* __restrict__ h,
                                                 const int* __restrict__ batch,
                                                 const float* __restrict__ wc1,
                                                 const float* __restrict__ bc1,
                                                 const float* __restrict__ gc1,
                                                 const float* __restrict__ bec1,
                                                 const float* __restrict__ mc1,
                                                 const float* __restrict__ vc1,
                                                 const float* __restrict__ wc2,
                                                 const float* __restrict__ bc2,
                                                 float* __restrict__ outp) {
  __shared__ int sb[2];
  __shared__ float ps[DD];
  __shared__ float ps2[DD];
  __shared__ float hh[64];
  int g = blockIdx.x, t = threadIdx.x;
  if (t < 2) sb[t] = lb(batch, NN, g + t);
  __syncthreads();
  int beg = sb[0], end = sb[1];
  int c = t & 127;
  int half = t >> 7;  // 0 or 1
  int m = (beg + end) >> 1;
  int lo0 = half ? m : beg;
  int hi0 = half ? end : m;
  float acc = 0.f;
  int n = lo0;
  for (; n + 4 <= hi0; n += 4) {
    float x0 = b2f(h[(size_t)(n + 0) * DD + c]);
    float x1 = b2f(h[(size_t)(n + 1) * DD + c]);
    float x2 = b2f(h[(size_t)(n + 2) * DD + c]);
    float x3 = b2f(h[(size_t)(n + 3) * DD + c]);
    acc += x0 + x1 + x2 + x3;
  }
  for (; n < hi0; ++n) acc += b2f(h[(size_t)n * DD + c]);
  if (half) ps2[c] = acc;
  else ps[c] = acc;
  __syncthreads();
  if (t < DD) {
    float inv = 1.0f / fmaxf((float)(end - beg), 1.0f);
    ps[t] = (ps[t] + ps2[t]) * inv;
  }
  __syncthreads();
  if (t < 64) {
    float a2 = 0.f;
#pragma unroll 8
    for (int k = 0; k < DD; ++k) a2 += ps[k] * wc1[k * 64 + t];
    float a = gc1[t] * rsqrtf(vc1[t] + EPS);
    float b2 = (bc1[t] - mc1[t]) * a + bec1[t];
    hh[t] = fmaxf(a2 * a + b2, 0.f);
  }
  __syncthreads();
  if (t < 2) {
    float a2 = bc2[t];
#pragma unroll
    for (int k = 0; k < 64; ++k) a2 += hh[k] * wc2[k * 2 + t];
    outp[g * 2 + t] = a2;
  }
}

extern "C" void kernel_launch(void* const* d_in, const int* in_sizes, int n_in,
                              void* d_out, int out_size, void* d_ws, size_t ws_size,
                              hipStream_t stream) {
  const float* x = (const float*)d_in[0];
  const int* ei = (const int*)d_in[1];
  const int* batch = (const int*)d_in[2];
  const float* w11 = (const float*)d_in[3];
  const float* b11 = (const float*)d_in[4];
  const float* g11 = (const float*)d_in[5];
  const float* be11 = (const float*)d_in[6];
  const float* m11 = (const float*)d_in[7];
  const float* v11 = (const float*)d_in[8];
  const float* w12 = (const float*)d_in[9];
  const float* b12 = (const float*)d_in[10];
  const float* g12 = (const float*)d_in[11];
  const float* be12 = (const float*)d_in[12];
  const float* m12 = (const float*)d_in[13];
  const float* v12 = (const float*)d_in[14];
  const float* w21 = (const float*)d_in[15];
  const float* b21 = (const float*)d_in[16];
  const float* g21 = (const float*)d_in[17];
  const float* be21 = (const float*)d_in[18];
  const float* m21 = (const float*)d_in[19];
  const float* v21 = (const float*)d_in[20];
  const float* w22 = (const float*)d_in[21];
  const float* b22 = (const float*)d_in[22];
  const float* g22 = (const float*)d_in[23];
  const float* be22 = (const float*)d_in[24];
  const float* m22 = (const float*)d_in[25];
  const float* v22 = (const float*)d_in[26];
  const float* wc1 = (const float*)d_in[27];
  const float* bc1 = (const float*)d_in[28];
  const float* gc1 = (const float*)d_in[29];
  const float* bec1 = (const float*)d_in[30];
  const float* mc1 = (const float*)d_in[31];
  const float* vc1 = (const float*)d_in[32];
  const float* wc2 = (const float*)d_in[33];
  const float* bc2 = (const float*)d_in[34];

  const size_t NB = (size_t)NN * DD;  // ushort elements per feature buffer
  ushort* XB = (ushort*)d_ws;
  ushort* AG = XB + NB;
  ushort* H1 = AG + NB;
  ushort* H2 = H1 + NB;
  int* row_ptr = (int*)(H2 + NB);      // NN+1
  int* buk_cnt = row_ptr + NN + 1;     // 256 (196 used)
  int* buk_base = buk_cnt + 256;       // spare
  int* csr_src = buk_base + 256;       // NE
  uint* buk_pairs = (uint*)(csr_src + NE);          // NBUK*CAP ~= 1.0M
  ushort* Wb = (ushort*)(buk_pairs + (size_t)NBUK * CAP);  // 4*16384
  float* albb = (float*)(Wb + 4 * DD * DD);         // 8*128

  const int gemmBlocks = (NN + 63) / 64;  // 782
  const int aggBlocks = NN / 8;           // 6250 (2 nodes/wave, 4 waves/block)

  // ---- prep + convert/bin + fill ----
  k_pre<<<65, 256, 0, stream>>>(w11, w12, w21, w22,
                                b11, g11, be11, m11, v11,
                                b12, g12, be12, m12, v12,
                                b21, g21, be21, m21, v21,
                                b22, g22, be22, m22, v22,
                                Wb, albb, buk_cnt);
  k_binC<<<CVTB + NBUK, 256, 0, stream>>>((const float4*)x, (short8*)XB, ei,
                                          buk_cnt, buk_pairs);
  k_bfill<<<NBUK, 256, 0, stream>>>(buk_pairs, buk_cnt, row_ptr, csr_src);

  // ---- GIN layer 1 ----
  k_agg<<<aggBlocks, 256, 0, stream>>>((const uint*)XB, row_ptr, csr_src, (uint*)AG);
  k_mlp<<<gemmBlocks, 256, 0, stream>>>(AG, Wb, Wb + DD * DD, albb, H1);

  // ---- GIN layer 2 ----
  k_agg<<<aggBlocks, 256, 0, stream>>>((const uint*)H1, row_ptr, csr_src, (uint*)AG);
  k_mlp<<<gemmBlocks, 256, 0, stream>>>(AG, Wb + 2 * DD * DD, Wb + 3 * DD * DD,
                                        albb + 4 * DD, H2);

  // ---- fused mean pool + classifier ----
  k_poolcls<<<GG, 256, 0, stream>>>(H2, batch, wc1, bc1, gc1, bec1, mc1, vc1,
                                    wc2, bc2, (float*)d_out);
}

// Round 13
// 147.789 us; speedup vs baseline: 1.5748x; 1.0180x over previous
//
#include <hip/hip_runtime.h>

#define NN 50000
#define NE 800000
#define DD 128
#define GG 2048
#define EPS 1e-5f
#define NBUK 196   // ceil(NN/256) dst-buckets of 256 nodes
#define CHUNK 4096 // edges per bin block
#define CAP 5120   // per-bucket slot capacity (mean 4096, sigma ~64)
#define CVTB 3125  // NN*DD/8/256

typedef __attribute__((ext_vector_type(8))) short short8;
typedef __attribute__((ext_vector_type(4))) float floatx4;

__device__ __forceinline__ ushort f2b(float f) {  // fp32 -> bf16 RNE
  uint u = __float_as_uint(f);
  uint r = ((u >> 16) & 1u) + 0x7fffu;
  return (ushort)((u + r) >> 16);
}
__device__ __forceinline__ float b2f(ushort h) {
  return __uint_as_float(((uint)h) << 16);
}
__device__ __forceinline__ float blo(uint u) { return __uint_as_float(u << 16); }
__device__ __forceinline__ float bhi(uint u) { return __uint_as_float(u & 0xffff0000u); }

// ---------------- prep: zero bucket counters, bf16+swizzle weights, BN folds --
__global__ __launch_bounds__(256) void k_pre(
    const float* __restrict__ W11, const float* __restrict__ W12,
    const float* __restrict__ W21, const float* __restrict__ W22,
    const float* __restrict__ b11, const float* __restrict__ g11,
    const float* __restrict__ be11, const float* __restrict__ m11,
    const float* __restrict__ v11,
    const float* __restrict__ b12, const float* __restrict__ g12,
    const float* __restrict__ be12, const float* __restrict__ m12,
    const float* __restrict__ v12,
    const float* __restrict__ b21, const float* __restrict__ g21,
    const float* __restrict__ be21, const float* __restrict__ m21,
    const float* __restrict__ v21,
    const float* __restrict__ b22, const float* __restrict__ g22,
    const float* __restrict__ be22, const float* __restrict__ m22,
    const float* __restrict__ v22,
    ushort* __restrict__ Wb, float* __restrict__ albb,
    int* __restrict__ buk_cnt) {
  int t = threadIdx.x;
  int b = blockIdx.x;
  if (b == 64) {
    buk_cnt[t] = 0;
    if (t < DD) {
      float a;
      a = g11[t] * rsqrtf(v11[t] + EPS);
      albb[0 * DD + t] = a;
      albb[1 * DD + t] = (b11[t] - m11[t]) * a + be11[t];
      a = g12[t] * rsqrtf(v12[t] + EPS);
      albb[2 * DD + t] = a;
      albb[3 * DD + t] = (b12[t] - m12[t]) * a + be12[t];
      a = g21[t] * rsqrtf(v21[t] + EPS);
      albb[4 * DD + t] = a;
      albb[5 * DD + t] = (b21[t] - m21[t]) * a + be21[t];
      a = g22[t] * rsqrtf(v22[t] + EPS);
      albb[6 * DD + t] = a;
      albb[7 * DD + t] = (b22[t] - m22[t]) * a + be22[t];
    }
    return;
  }
  const float* Ws[4] = {W11, W12, W21, W22};
  int widx = b >> 4;
  int idx = (b & 15) * 256 + t;  // 0..4095
  int c = idx >> 5;
  int k0 = (idx & 31) * 4;
  const float* W = Ws[widx];
  ushort4 p;
  p.x = f2b(W[(k0 + 0) * DD + c]);
  p.y = f2b(W[(k0 + 1) * DD + c]);
  p.z = f2b(W[(k0 + 2) * DD + c]);
  p.w = f2b(W[(k0 + 3) * DD + c]);
  *(ushort4*)&Wb[(size_t)widx * DD * DD + c * DD + (k0 ^ ((c & 7) << 3))] = p;
}

// ---------------- fused fp32->bf16 feature convert + edge binning ------------
__global__ __launch_bounds__(256) void k_binC(const float4* __restrict__ x,
                                              short8* __restrict__ xb,
                                              const int* __restrict__ ei,
                                              int* __restrict__ buk_cnt,
                                              uint* __restrict__ buk_pairs) {
  __shared__ int hist[256];
  __shared__ int gbase[256];
  __shared__ int lcur[256];
  int t = threadIdx.x;
  if (blockIdx.x < CVTB) {
    int i = blockIdx.x * 256 + t;
    float4 a = x[2 * i], c = x[2 * i + 1];
    short8 v;
    v[0] = (short)f2b(a.x); v[1] = (short)f2b(a.y);
    v[2] = (short)f2b(a.z); v[3] = (short)f2b(a.w);
    v[4] = (short)f2b(c.x); v[5] = (short)f2b(c.y);
    v[6] = (short)f2b(c.z); v[7] = (short)f2b(c.w);
    xb[i] = v;
    return;
  }
  int blk = blockIdx.x - CVTB;
  int e0 = blk * CHUNK;
  int nE = min(CHUNK, NE - e0);
  hist[t] = 0;
  lcur[t] = 0;
  gbase[t] = 0;
  __syncthreads();
  uint pk[16];
#pragma unroll
  for (int i = 0; i < 16; ++i) {
    int off = i * 256 + t;
    if (off < nE) {
      int e = e0 + off;
      int s = ei[e], d = ei[NE + e];
      int b = d >> 8;
      pk[i] = ((uint)b << 24) | ((uint)(d & 255) << 16) | (uint)s;
      atomicAdd(&hist[b], 1);
    } else {
      pk[i] = 0xffffffffu;
    }
  }
  __syncthreads();
  if (t < NBUK && hist[t] > 0) gbase[t] = atomicAdd(&buk_cnt[t], hist[t]);
  __syncthreads();
#pragma unroll
  for (int i = 0; i < 16; ++i) {
    if (pk[i] != 0xffffffffu) {
      int b = pk[i] >> 24;
      int lo = atomicAdd(&lcur[b], 1);
      int off = gbase[b] + lo;
      if (off < CAP) buk_pairs[(size_t)b * CAP + off] = pk[i];
    }
  }
}

// ---------------- per-bucket CSR fill (bucket scan inlined) ----------------
__global__ __launch_bounds__(256) void k_bfill(const uint* __restrict__ buk_pairs,
                                               const int* __restrict__ buk_cnt,
                                               int* __restrict__ row_ptr,
                                               int* __restrict__ csr_src) {
  __shared__ int sc[256];
  __shared__ int deg[256];
  __shared__ int pos[256];
  int b = blockIdx.x, t = threadIdx.x;
  int c = (t < NBUK) ? min(buk_cnt[t], CAP) : 0;
  sc[t] = c;
  __syncthreads();
  int s1 = c;
  for (int off = 1; off < 256; off <<= 1) {
    int o = (t >= off) ? sc[t - off] : 0;
    __syncthreads();
    s1 += o;
    sc[t] = s1;
    __syncthreads();
  }
  int beg = (b == 0) ? 0 : sc[b - 1];
  int cnt = sc[b] - beg;
  const uint* src = buk_pairs + (size_t)b * CAP;
  deg[t] = 0;
  __syncthreads();
  for (int i = t; i < cnt; i += 256) {
    atomicAdd(&deg[(src[i] >> 16) & 255], 1);
  }
  __syncthreads();
  int d = deg[t];
  int sum = d;
  pos[t] = sum;
  __syncthreads();
  for (int off = 1; off < 256; off <<= 1) {
    int o = (t >= off) ? pos[t - off] : 0;
    __syncthreads();
    sum += o;
    pos[t] = sum;
    __syncthreads();
  }
  int myStart = beg + sum - d;
  int node = b * 256 + t;
  if (node < NN) row_ptr[node] = myStart;
  if (node == NN - 1) row_ptr[NN] = NE;
  __syncthreads();
  pos[t] = myStart;
  __syncthreads();
  for (int i = t; i < cnt; i += 256) {
    uint p = src[i];
    int lo = atomicAdd(&pos[(p >> 16) & 255], 1);
    csr_src[lo] = (int)(p & 0xffffu);
  }
}

// ---------------- aggregation: out[n] = x[n] + sum_{j->n} x[j] ----------------
// TWO nodes per wave (32 lanes each, lane owns 4 bf16 cols via uint2).
// At the L2-miss-path BW floor (~3.2 TB/s); keep LDS-free (R10 lesson).
__global__ __launch_bounds__(256) void k_agg(const uint* __restrict__ X,
                                             const int* __restrict__ row_ptr,
                                             const int* __restrict__ csr_src,
                                             uint* __restrict__ out) {
  int wid = (blockIdx.x * 256 + threadIdx.x) >> 6;
  int l = threadIdx.x & 63;
  int g = l >> 5, sl = l & 31;
  int node = wid * 2 + g;
  if (node >= NN) return;
  int base = g * 32;
  const uint2* Xr = (const uint2*)(X + (size_t)node * 64);
  uint2 s0 = Xr[sl];
  float a0 = blo(s0.x), a1 = bhi(s0.x), a2 = blo(s0.y), a3 = bhi(s0.y);
  int beg = row_ptr[node], end = row_ptr[node + 1];
  for (int i = beg; i < end; i += 32) {
    int idx = i + sl;
    int my = (idx < end) ? __builtin_nontemporal_load(csr_src + idx) : 0;
    int cnt = min(32, end - i);
    int j = 0;
    for (; j + 8 <= cnt; j += 8) {
      int n0 = __shfl(my, base + j + 0);
      int n1 = __shfl(my, base + j + 1);
      int n2 = __shfl(my, base + j + 2);
      int n3 = __shfl(my, base + j + 3);
      int n4 = __shfl(my, base + j + 4);
      int n5 = __shfl(my, base + j + 5);
      int n6 = __shfl(my, base + j + 6);
      int n7 = __shfl(my, base + j + 7);
      uint2 v0 = *(const uint2*)(X + (size_t)n0 * 64 + sl * 2);
      uint2 v1 = *(const uint2*)(X + (size_t)n1 * 64 + sl * 2);
      uint2 v2 = *(const uint2*)(X + (size_t)n2 * 64 + sl * 2);
      uint2 v3 = *(const uint2*)(X + (size_t)n3 * 64 + sl * 2);
      uint2 v4 = *(const uint2*)(X + (size_t)n4 * 64 + sl * 2);
      uint2 v5 = *(const uint2*)(X + (size_t)n5 * 64 + sl * 2);
      uint2 v6 = *(const uint2*)(X + (size_t)n6 * 64 + sl * 2);
      uint2 v7 = *(const uint2*)(X + (size_t)n7 * 64 + sl * 2);
      a0 += blo(v0.x); a1 += bhi(v0.x); a2 += blo(v0.y); a3 += bhi(v0.y);
      a0 += blo(v1.x); a1 += bhi(v1.x); a2 += blo(v1.y); a3 += bhi(v1.y);
      a0 += blo(v2.x); a1 += bhi(v2.x); a2 += blo(v2.y); a3 += bhi(v2.y);
      a0 += blo(v3.x); a1 += bhi(v3.x); a2 += blo(v3.y); a3 += bhi(v3.y);
      a0 += blo(v4.x); a1 += bhi(v4.x); a2 += blo(v4.y); a3 += bhi(v4.y);
      a0 += blo(v5.x); a1 += bhi(v5.x); a2 += blo(v5.y); a3 += bhi(v5.y);
      a0 += blo(v6.x); a1 += bhi(v6.x); a2 += blo(v6.y); a3 += bhi(v6.y);
      a0 += blo(v7.x); a1 += bhi(v7.x); a2 += blo(v7.y); a3 += bhi(v7.y);
    }
    for (; j + 4 <= cnt; j += 4) {
      int n0 = __shfl(my, base + j + 0);
      int n1 = __shfl(my, base + j + 1);
      int n2 = __shfl(my, base + j + 2);
      int n3 = __shfl(my, base + j + 3);
      uint2 v0 = *(const uint2*)(X + (size_t)n0 * 64 + sl * 2);
      uint2 v1 = *(const uint2*)(X + (size_t)n1 * 64 + sl * 2);
      uint2 v2 = *(const uint2*)(X + (size_t)n2 * 64 + sl * 2);
      uint2 v3 = *(const uint2*)(X + (size_t)n3 * 64 + sl * 2);
      a0 += blo(v0.x); a1 += bhi(v0.x); a2 += blo(v0.y); a3 += bhi(v0.y);
      a0 += blo(v1.x); a1 += bhi(v1.x); a2 += blo(v1.y); a3 += bhi(v1.y);
      a0 += blo(v2.x); a1 += bhi(v2.x); a2 += blo(v2.y); a3 += bhi(v2.y);
      a0 += blo(v3.x); a1 += bhi(v3.x); a2 += blo(v3.y); a3 += bhi(v3.y);
    }
    for (; j < cnt; ++j) {
      int s = __shfl(my, base + j);
      uint2 v = *(const uint2*)(X + (size_t)s * 64 + sl * 2);
      a0 += blo(v.x); a1 += bhi(v.x); a2 += blo(v.y); a3 += bhi(v.y);
    }
  }
  uint2 o;
  o.x = (uint)f2b(a0) | ((uint)f2b(a1) << 16);
  o.y = (uint)f2b(a2) | ((uint)f2b(a3) << 16);
  *(uint2*)(out + (size_t)node * 64 + sl * 2) = o;
}

// ---------------- fused MLP: out = relu(bn2(relu(bn1(A@W1))@W2)), bf16 --------
// 128 rows/block in two 64-row halves; each wave runs both halves through its
// own 16-row slice of `mid` (wave-local -> no extra LDS, no extra barriers).
// Halves block count and W-staging traffic vs the 64-row version.
__global__ __launch_bounds__(256) void k_mlp(const ushort* __restrict__ A,
                                             const ushort* __restrict__ Wb1,
                                             const ushort* __restrict__ Wb2,
                                             const float* __restrict__ albb,
                                             ushort* __restrict__ out) {
  __shared__ ushort Wt[DD * DD];   // 32 KB, reused for W1 then W2
  __shared__ ushort mid[64 * DD];  // 16 KB, wave-local 16-row slices
  __shared__ float al1[DD], bb1[DD], al2[DD], bb2[DD];
  int t = threadIdx.x;
  for (int ii = t; ii < 2048; ii += 256) ((short8*)Wt)[ii] = ((const short8*)Wb1)[ii];
  if (t < DD) {
    al1[t] = albb[0 * DD + t];
    bb1[t] = albb[1 * DD + t];
    al2[t] = albb[2 * DD + t];
    bb2[t] = albb[3 * DD + t];
  }
  int w = t >> 6, l = t & 63;
  int lr = l & 15, lg = l >> 4;
  int rowA = blockIdx.x * 128 + w * 16;  // half A wave rows
  int rowB = rowA + 64;                  // half B wave rows
  int arA = min(rowA + lr, NN - 1);
  int arB = min(rowB + lr, NN - 1);
  const short8* ArA = (const short8*)(A + (size_t)arA * DD);
  const short8* ArB = (const short8*)(A + (size_t)arB * DD);
  short8 aA0 = ArA[0 * 4 + lg];
  short8 aA1 = ArA[1 * 4 + lg];
  short8 aA2 = ArA[2 * 4 + lg];
  short8 aA3 = ArA[3 * 4 + lg];
  short8 aB0 = ArB[0 * 4 + lg];
  short8 aB1 = ArB[1 * 4 + lg];
  short8 aB2 = ArB[2 * 4 + lg];
  short8 aB3 = ArB[3 * 4 + lg];
  __syncthreads();  // Wt(W1) staged

  int mrowb = w * 16;
  int mr = mrowb + lr;
  int msw = (mr & 7) << 3;
  const ushort* mrp = mid + mr * DD;

  // ---- GEMM1 half A -> mid (wave-local rows) ----
#pragma unroll
  for (int ct = 0; ct < 8; ++ct) {
    int c = ct * 16 + lr;
    int sw = (c & 7) << 3;
    const ushort* wr = Wt + c * DD;
    short8 b0 = *(const short8*)(wr + ((0 * 32 + lg * 8) ^ sw));
    short8 b1 = *(const short8*)(wr + ((1 * 32 + lg * 8) ^ sw));
    short8 b2 = *(const short8*)(wr + ((2 * 32 + lg * 8) ^ sw));
    short8 b3 = *(const short8*)(wr + ((3 * 32 + lg * 8) ^ sw));
    floatx4 acc = {0.f, 0.f, 0.f, 0.f};
    acc = __builtin_amdgcn_mfma_f32_16x16x32_bf16(aA0, b0, acc, 0, 0, 0);
    acc = __builtin_amdgcn_mfma_f32_16x16x32_bf16(aA1, b1, acc, 0, 0, 0);
    acc = __builtin_amdgcn_mfma_f32_16x16x32_bf16(aA2, b2, acc, 0, 0, 0);
    acc = __builtin_amdgcn_mfma_f32_16x16x32_bf16(aA3, b3, acc, 0, 0, 0);
    float alc = al1[c], bbc = bb1[c];
#pragma unroll
    for (int reg = 0; reg < 4; ++reg) {
      int row = mrowb + lg * 4 + reg;
      mid[row * DD + (c ^ ((row & 7) << 3))] = f2b(fmaxf(acc[reg] * alc + bbc, 0.f));
    }
  }
  // wave-local readback of half-A mid frags (no barrier needed)
  short8 cA0 = *(const short8*)(mrp + ((0 * 32 + lg * 8) ^ msw));
  short8 cA1 = *(const short8*)(mrp + ((1 * 32 + lg * 8) ^ msw));
  short8 cA2 = *(const short8*)(mrp + ((2 * 32 + lg * 8) ^ msw));
  short8 cA3 = *(const short8*)(mrp + ((3 * 32 + lg * 8) ^ msw));

  // ---- GEMM1 half B -> mid (same wave-local rows, reused) ----
#pragma unroll
  for (int ct = 0; ct < 8; ++ct) {
    int c = ct * 16 + lr;
    int sw = (c & 7) << 3;
    const ushort* wr = Wt + c * DD;
    short8 b0 = *(const short8*)(wr + ((0 * 32 + lg * 8) ^ sw));
    short8 b1 = *(const short8*)(wr + ((1 * 32 + lg * 8) ^ sw));
    short8 b2 = *(const short8*)(wr + ((2 * 32 + lg * 8) ^ sw));
    short8 b3 = *(const short8*)(wr + ((3 * 32 + lg * 8) ^ sw));
    floatx4 acc = {0.f, 0.f, 0.f, 0.f};
    acc = __builtin_amdgcn_mfma_f32_16x16x32_bf16(aB0, b0, acc, 0, 0, 0);
    acc = __builtin_amdgcn_mfma_f32_16x16x32_bf16(aB1, b1, acc, 0, 0, 0);
    acc = __builtin_amdgcn_mfma_f32_16x16x32_bf16(aB2, b2, acc, 0, 0, 0);
    acc = __builtin_amdgcn_mfma_f32_16x16x32_bf16(aB3, b3, acc, 0, 0, 0);
    float alc = al1[c], bbc = bb1[c];
#pragma unroll
    for (int reg = 0; reg < 4; ++reg) {
      int row = mrowb + lg * 4 + reg;
      mid[row * DD + (c ^ ((row & 7) << 3))] = f2b(fmaxf(acc[reg] * alc + bbc, 0.f));
    }
  }
  short8 cB0 = *(const short8*)(mrp + ((0 * 32 + lg * 8) ^ msw));
  short8 cB1 = *(const short8*)(mrp + ((1 * 32 + lg * 8) ^ msw));
  short8 cB2 = *(const short8*)(mrp + ((2 * 32 + lg * 8) ^ msw));
  short8 cB3 = *(const short8*)(mrp + ((3 * 32 + lg * 8) ^ msw));

  __syncthreads();  // all W1 reads done
  for (int ii = t; ii < 2048; ii += 256) ((short8*)Wt)[ii] = ((const short8*)Wb2)[ii];
  __syncthreads();  // Wt(W2) staged

  // ---- GEMM2 half A -> global ----
#pragma unroll
  for (int ct = 0; ct < 8; ++ct) {
    int c = ct * 16 + lr;
    int sw = (c & 7) << 3;
    const ushort* wr = Wt + c * DD;
    short8 b0 = *(const short8*)(wr + ((0 * 32 + lg * 8) ^ sw));
    short8 b1 = *(const short8*)(wr + ((1 * 32 + lg * 8) ^ sw));
    short8 b2 = *(const short8*)(wr + ((2 * 32 + lg * 8) ^ sw));
    short8 b3 = *(const short8*)(wr + ((3 * 32 + lg * 8) ^ sw));
    floatx4 acc = {0.f, 0.f, 0.f, 0.f};
    acc = __builtin_amdgcn_mfma_f32_16x16x32_bf16(cA0, b0, acc, 0, 0, 0);
    acc = __builtin_amdgcn_mfma_f32_16x16x32_bf16(cA1, b1, acc, 0, 0, 0);
    acc = __builtin_amdgcn_mfma_f32_16x16x32_bf16(cA2, b2, acc, 0, 0, 0);
    acc = __builtin_amdgcn_mfma_f32_16x16x32_bf16(cA3, b3, acc, 0, 0, 0);
    float alc = al2[c], bbc = bb2[c];
#pragma unroll
    for (int reg = 0; reg < 4; ++reg) {
      int r = rowA + lg * 4 + reg;
      if (r < NN) {
        out[(size_t)r * DD + c] = f2b(fmaxf(acc[reg] * alc + bbc, 0.f));
      }
    }
  }
  // ---- GEMM2 half B -> global ----
#pragma unroll
  for (int ct = 0; ct < 8; ++ct) {
    int c = ct * 16 + lr;
    int sw = (c & 7) << 3;
    const ushort* wr = Wt + c * DD;
    short8 b0 = *(const short8*)(wr + ((0 * 32 + lg * 8) ^ sw));
    short8 b1 = *(const short8*)(wr + ((1 * 32 + lg * 8) ^ sw));
    short8 b2 = *(const short8*)(wr + ((2 * 32 + lg * 8) ^ sw));
    short8 b3 = *(const short8*)(wr + ((3 * 32 + lg * 8) ^ sw));
    floatx4 acc = {0.f, 0.f, 0.f, 0.f};
    acc = __builtin_amdgcn_mfma_f32_16x16x32_bf16(cB0, b0, acc, 0, 0, 0);
    acc = __builtin_amdgcn_mfma_f32_16x16x32_bf16(cB1, b1, acc, 0, 0, 0);
    acc = __builtin_amdgcn_mfma_f32_16x16x32_bf16(cB2, b2, acc, 0, 0, 0);
    acc = __builtin_amdgcn_mfma_f32_16x16x32_bf16(cB3, b3, acc, 0, 0, 0);
    float alc = al2[c], bbc = bb2[c];
#pragma unroll
    for (int reg = 0; reg < 4; ++reg) {
      int r = rowB + lg * 4 + reg;
      if (r < NN) {
        out[(size_t)r * DD + c] = f2b(fmaxf(acc[reg] * alc + bbc, 0.f));
      }
    }
  }
}

// ---------------- fused mean-pool + classifier (batch sorted) ----------------
__device__ __forceinline__ int lb(const int* __restrict__ a, int n, int v) {
  int lo = 0, hi = n;
  while (lo < hi) {
    int mid = (lo + hi) >> 1;
    if (a[mid] < v) lo = mid + 1;
    else hi = mid;
  }
  return lo;
}

__global__ __launch_bounds__(256) void k_poolcls(const ushort* __restrict__ h,
                                                 const int* __restrict__ batch,
                                                 const float* __restrict__ wc1,
                                                 const float* __restrict__ bc1,
                                                 const float* __restrict__ gc1,
                                                 const float* __restrict__ bec1,
                                                 const float* __restrict__ mc1,
                                                 const float* __restrict__ vc1,
                                                 const float* __restrict__ wc2,
                                                 const float* __restrict__ bc2,
                                                 float* __restrict__ outp) {
  __shared__ int sb[2];
  __shared__ float ps[DD];
  __shared__ float ps2[DD];
  __shared__ float hh[64];
  int g = blockIdx.x, t = threadIdx.x;
  if (t < 2) sb[t] = lb(batch, NN, g + t);
  __syncthreads();
  int beg = sb[0], end = sb[1];
  int c = t & 127;
  int half = t >> 7;  // 0 or 1
  int m = (beg + end) >> 1;
  int lo0 = half ? m : beg;
  int hi0 = half ? end : m;
  float acc = 0.f;
  int n = lo0;
  for (; n + 4 <= hi0; n += 4) {
    float x0 = b2f(h[(size_t)(n + 0) * DD + c]);
    float x1 = b2f(h[(size_t)(n + 1) * DD + c]);
    float x2 = b2f(h[(size_t)(n + 2) * DD + c]);
    float x3 = b2f(h[(size_t)(n + 3) * DD + c]);
    acc += x0 + x1 + x2 + x3;
  }
  for (; n < hi0; ++n) acc += b2f(h[(size_t)n * DD + c]);
  if (half) ps2[c] = acc;
  else ps[c] = acc;
  __syncthreads();
  if (t < DD) {
    float inv = 1.0f / fmaxf((float)(end - beg), 1.0f);
    ps[t] = (ps[t] + ps2[t]) * inv;
  }
  __syncthreads();
  if (t < 64) {
    float a2 = 0.f;
#pragma unroll 8
    for (int k = 0; k < DD; ++k) a2 += ps[k] * wc1[k * 64 + t];
    float a = gc1[t] * rsqrtf(vc1[t] + EPS);
    float b2 = (bc1[t] - mc1[t]) * a + bec1[t];
    hh[t] = fmaxf(a2 * a + b2, 0.f);
  }
  __syncthreads();
  if (t < 2) {
    float a2 = bc2[t];
#pragma unroll
    for (int k = 0; k < 64; ++k) a2 += hh[k] * wc2[k * 2 + t];
    outp[g * 2 + t] = a2;
  }
}

extern "C" void kernel_launch(void* const* d_in, const int* in_sizes, int n_in,
                              void* d_out, int out_size, void* d_ws, size_t ws_size,
                              hipStream_t stream) {
  const float* x = (const float*)d_in[0];
  const int* ei = (const int*)d_in[1];
  const int* batch = (const int*)d_in[2];
  const float* w11 = (const float*)d_in[3];
  const float* b11 = (const float*)d_in[4];
  const float* g11 = (const float*)d_in[5];
  const float* be11 = (const float*)d_in[6];
  const float* m11 = (const float*)d_in[7];
  const float* v11 = (const float*)d_in[8];
  const float* w12 = (const float*)d_in[9];
  const float* b12 = (const float*)d_in[10];
  const float* g12 = (const float*)d_in[11];
  const float* be12 = (const float*)d_in[12];
  const float* m12 = (const float*)d_in[13];
  const float* v12 = (const float*)d_in[14];
  const float* w21 = (const float*)d_in[15];
  const float* b21 = (const float*)d_in[16];
  const float* g21 = (const float*)d_in[17];
  const float* be21 = (const float*)d_in[18];
  const float* m21 = (const float*)d_in[19];
  const float* v21 = (const float*)d_in[20];
  const float* w22 = (const float*)d_in[21];
  const float* b22 = (const float*)d_in[22];
  const float* g22 = (const float*)d_in[23];
  const float* be22 = (const float*)d_in[24];
  const float* m22 = (const float*)d_in[25];
  const float* v22 = (const float*)d_in[26];
  const float* wc1 = (const float*)d_in[27];
  const float* bc1 = (const float*)d_in[28];
  const float* gc1 = (const float*)d_in[29];
  const float* bec1 = (const float*)d_in[30];
  const float* mc1 = (const float*)d_in[31];
  const float* vc1 = (const float*)d_in[32];
  const float* wc2 = (const float*)d_in[33];
  const float* bc2 = (const float*)d_in[34];

  const size_t NB = (size_t)NN * DD;  // ushort elements per feature buffer
  ushort* XB = (ushort*)d_ws;
  ushort* AG = XB + NB;
  ushort* H1 = AG + NB;
  ushort* H2 = H1 + NB;
  int* row_ptr = (int*)(H2 + NB);      // NN+1
  int* buk_cnt = row_ptr + NN + 1;     // 256 (196 used)
  int* buk_base = buk_cnt + 256;       // spare
  int* csr_src = buk_base + 256;       // NE
  uint* buk_pairs = (uint*)(csr_src + NE);          // NBUK*CAP ~= 1.0M
  ushort* Wb = (ushort*)(buk_pairs + (size_t)NBUK * CAP);  // 4*16384
  float* albb = (float*)(Wb + 4 * DD * DD);         // 8*128

  const int gemmBlocks = (NN + 127) / 128;  // 391
  const int aggBlocks = NN / 8;             // 6250 (2 nodes/wave)

  // ---- prep + convert/bin + fill ----
  k_pre<<<65, 256, 0, stream>>>(w11, w12, w21, w22,
                                b11, g11, be11, m11, v11,
                                b12, g12, be12, m12, v12,
                                b21, g21, be21, m21, v21,
                                b22, g22, be22, m22, v22,
                                Wb, albb, buk_cnt);
  k_binC<<<CVTB + NBUK, 256, 0, stream>>>((const float4*)x, (short8*)XB, ei,
                                          buk_cnt, buk_pairs);
  k_bfill<<<NBUK, 256, 0, stream>>>(buk_pairs, buk_cnt, row_ptr, csr_src);

  // ---- GIN layer 1 ----
  k_agg<<<aggBlocks, 256, 0, stream>>>((const uint*)XB, row_ptr, csr_src, (uint*)AG);
  k_mlp<<<gemmBlocks, 256, 0, stream>>>(AG, Wb, Wb + DD * DD, albb, H1);

  // ---- GIN layer 2 ----
  k_agg<<<aggBlocks, 256, 0, stream>>>((const uint*)H1, row_ptr, csr_src, (uint*)AG);
  k_mlp<<<gemmBlocks, 256, 0, stream>>>(AG, Wb + 2 * DD * DD, Wb + 3 * DD * DD,
                                        albb + 4 * DD, H2);

  // ---- fused mean pool + classifier ----
  k_poolcls<<<GG, 256, 0, stream>>>(H2, batch, wc1, bc1, gc1, bec1, mc1, vc1,
                                    wc2, bc2, (float*)d_out);
}